// Round 1
// baseline (507.963 us; speedup 1.0000x reference)
//
#include <hip/hip_runtime.h>
#include <hip/hip_bf16.h>

#define NN 200000
#define NE 600000
#define NG 1024
#define HH 512
#define ECAP 1024

typedef short short8 __attribute__((ext_vector_type(8)));
typedef float f32x4 __attribute__((ext_vector_type(4)));

__device__ __forceinline__ unsigned short f2bf(float f){
  unsigned u = __float_as_uint(f);
  u += 0x7fffu + ((u >> 16) & 1u);
  return (unsigned short)(u >> 16);
}
__device__ __forceinline__ float bf2f(unsigned short h){
  return __uint_as_float(((unsigned)h) << 16);
}

// packed f32x8 -> bf16x8 (RTNE)
__device__ __forceinline__ short8 cvt8pk(float4 a, float4 b){
  union { short8 s; __hip_bfloat162 h[4]; } u;
  u.h[0] = __float22bfloat162_rn(make_float2(a.x, a.y));
  u.h[1] = __float22bfloat162_rn(make_float2(a.z, a.w));
  u.h[2] = __float22bfloat162_rn(make_float2(b.x, b.y));
  u.h[3] = __float22bfloat162_rn(make_float2(b.z, b.w));
  return u.s;
}

// analytic gelu (kept for the tiny 1M-element GEMM epilogues only)
__device__ __forceinline__ float gelu_f(float x){
  float p = __builtin_fmaf(x*x, -0.10294325f, -2.3022085f);
  float e = __builtin_amdgcn_exp2f(x * p);
  return x * __builtin_amdgcn_rcpf(1.0f + e);
}

// ========== kpre: w1 prep (bias folded into K rows as hi+lo bf16) + nstart +
//            B-matrix bf16 hi/lo pre-split (transposed) + gelu LUT + cnt/perm2d zero ====
__global__ __launch_bounds__(256) void kpre(
    const float* __restrict__ nfw1, const float* __restrict__ nfb1,
    const float* __restrict__ nfg1, const float* __restrict__ nfbe1,
    const float* __restrict__ efw1, const float* __restrict__ efb1,
    const float* __restrict__ efg1, const float* __restrict__ efbe1,
    const float* __restrict__ w2n, const float* __restrict__ w2e,
    const float* __restrict__ ow1, const float* __restrict__ ow2,
    const int* __restrict__ bidx,
    unsigned short* __restrict__ w1nT, unsigned short* __restrict__ w1eT,
    unsigned short* __restrict__ Bh1, unsigned short* __restrict__ Bl1,
    unsigned short* __restrict__ Bh2, unsigned short* __restrict__ Bl2,
    unsigned short* __restrict__ Bh3, unsigned short* __restrict__ Bl3,
    float2* __restrict__ tab, int* __restrict__ cnt, int* __restrict__ nstart,
    int4* __restrict__ pz){
  const float rs = 0.99999500003750f;   // 1/sqrt(1+1e-5)
  const int b = blockIdx.x, t = threadIdx.x;
  if (b < 192){
    int tid = b*256 + t;
    if (tid < 512*64){
      int c = tid >> 6, k = tid & 63;
      float w = 0.0f;
      if (k < 41) w = nfw1[k*HH + c] * nfg1[c] * rs;
      else if (k == 41 || k == 42){
        float beff = nfb1[c]*nfg1[c]*rs + nfbe1[c];
        if (k == 41) w = bf2f(f2bf(beff));        // bias-hi (stored exactly)
        else         w = beff - bf2f(f2bf(beff)); // bias-lo
      }
      w1nT[tid] = f2bf(w);
    } else {
      int u = tid - 512*64; int c = u >> 5, k = u & 31;
      float w = 0.0f;
      if (k < 16) w = efw1[k*HH + c] * efg1[c] * rs;
      else if (k == 16 || k == 17){
        float beff = efb1[c]*efg1[c]*rs + efbe1[c];
        if (k == 16) w = bf2f(f2bf(beff));
        else         w = beff - bf2f(f2bf(beff));
      }
      w1eT[u] = f2bf(w);
    }
  } else if (b < 974){
    int i = (b-192)*256 + t;
    if (i < NN){
      int g0 = bidx[i];
      int g1 = (i+1 < NN) ? bidx[i+1] : NG;
      for (int g = g0+1; g <= g1; ++g) nstart[g] = i+1;
      if (i == 0) for (int g = 0; g <= g0; ++g) nstart[g] = 0;
    }
  } else if (b < 3022){
    int idx = (b-974)*256 + t;                 // 1024x512 stacked [w2n; w2e]
    int k = idx >> 9, c = idx & 511;
    float v = (k < 512) ? w2n[k*HH + c] : w2e[(k-512)*HH + c];
    unsigned short h = f2bf(v);
    Bh1[(size_t)c*1024 + k] = h;
    Bl1[(size_t)c*1024 + k] = f2bf(v - bf2f(h));
  } else if (b < 4046){
    int idx = (b-3022)*256 + t;
    int k = idx >> 9, c = idx & 511;
    float v = ow1[k*HH + c];
    unsigned short h = f2bf(v);
    Bh2[(size_t)c*512 + k] = h;
    Bl2[(size_t)c*512 + k] = f2bf(v - bf2f(h));
  } else if (b < 5070){
    int idx = (b-4046)*256 + t;
    int k = idx >> 9, c = idx & 511;
    float v = ow2[k*HH + c];
    unsigned short h = f2bf(v);
    Bh3[(size_t)c*512 + k] = h;
    Bl3[(size_t)c*512 + k] = f2bf(v - bf2f(h));
  } else if (b == 5070){
    // gelu LUT: Qhat(v) = 0.5*v*erfc(v/sqrt(2)) on v in [0,4), step 1/64, + slope
    float v0 = (float)t * 0.015625f;
    float v1 = v0 + 0.015625f;
    float q0 = 0.5f * v0 * erfcf(v0 * 0.70710678f);
    float q1 = 0.5f * v1 * erfcf(v1 * 0.70710678f);
    tab[t] = make_float2(q0, q1 - q0);
    cnt[t] = 0; cnt[t+256] = 0; cnt[t+512] = 0; cnt[t+768] = 0;
  } else {
    int idx = (b-5071)*256 + t;                // zero perm2d (1M ints)
    pz[idx] = make_int4(0,0,0,0);
  }
}

// ========== kscatter: atomic-cursor bucket scatter (replaces histogram+scan+scatter) ==
__global__ __launch_bounds__(256) void kscatter(const int* __restrict__ eidx,
    const int* __restrict__ bidx, int* __restrict__ cnt, int* __restrict__ perm2d){
  int e = blockIdx.x*256 + threadIdx.x;
  if (e < NE){
    int g = bidx[eidx[e]];
    int p = atomicAdd(&cnt[g], 1);
    if (p < ECAP) perm2d[(g << 10) + p] = e;
  }
}

// gelu(x) = 0.5x + 0.5|x| - Qhat(|x|), Qhat via LDS LUT + lerp (zero transcendentals)
#define GELU_ACC(x_, dst_) { \
  float ax_ = __builtin_fabsf(x_); \
  float tt_ = fminf(ax_ * 64.0f, 254.99f); \
  int ix_ = (int)tt_; \
  float fr_ = tt_ - (float)ix_; \
  float2 te_ = tabs[ix_]; \
  float Q_ = __builtin_fmaf(fr_, te_.y, te_.x); \
  float r_ = __builtin_fmaf(ax_, 0.5f, -Q_); \
  dst_ += __builtin_fmaf(x_, 0.5f, r_); }

#define GELU_ACC_M(x_, dst_, ok_) { \
  float ax_ = __builtin_fabsf(x_); \
  float tt_ = fminf(ax_ * 64.0f, 254.99f); \
  int ix_ = (int)tt_; \
  float fr_ = tt_ - (float)ix_; \
  float2 te_ = tabs[ix_]; \
  float Q_ = __builtin_fmaf(fr_, te_.y, te_.x); \
  float r_ = __builtin_fmaf(ax_, 0.5f, -Q_); \
  float g_ = __builtin_fmaf(x_, 0.5f, r_); \
  dst_ += (ok_) ? g_ : 0.0f; }

// ========== fused first layers: segment-sum of gelu(row@W1) with LUT gelu ==========
__global__ __launch_bounds__(256) void kmain(
    const float* __restrict__ nf, const float* __restrict__ dp, const int* __restrict__ ny,
    const int* __restrict__ nstart, const float* __restrict__ ef,
    const int* __restrict__ perm2d, const int* __restrict__ cnt,
    const unsigned short* __restrict__ w1nT, const unsigned short* __restrict__ w1eT,
    const float2* __restrict__ tab,
    unsigned short* __restrict__ Sh, unsigned short* __restrict__ Sl){
  __shared__ float2 tabs[256];
  const int t = threadIdx.x;
  tabs[t] = tab[t];
  __syncthreads();
  const int lane = t & 63, w = t >> 6;
  const int q = lane >> 4, m = lane & 15;
  const short8 zz = {0,0,0,0,0,0,0,0};
  const f32x4 zq = {0.f,0.f,0.f,0.f};
  if (blockIdx.x < 2048){
    // ---------------- EDGE:  2 blocks/graph, wave owns 64 cols ----------------
    const int g = blockIdx.x >> 1;
    const int c0 = ((blockIdx.x & 1) << 8) + (w << 6);
    short8 bfr[4]; float colacc[4] = {0.f,0.f,0.f,0.f};
#pragma unroll
    for (int nt=0; nt<4; ++nt)
      bfr[nt] = *(const short8*)(w1eT + ((c0 + (nt<<4) + m) << 5) + (q << 3));
    const int base = g << 10;
    const int s1 = cnt[g];
    const int nfull = s1 >> 4;
    int rb = 0;
    for (int ch=0; ch<nfull; ++ch, rb += 16){
      int e = perm2d[base + rb + m];
      short8 f;
      if (q < 2){
        const float4* ap = (const float4*)(ef + (size_t)e*16 + (q<<3));
        f = cvt8pk(ap[0], ap[1]);
      } else if (q == 2){
        f = zz; f[0] = (short)0x3F80; f[1] = (short)0x3F80;  // k=16,17 -> bias hi+lo
      } else f = zz;
#pragma unroll
      for (int nt=0; nt<4; ++nt){
        f32x4 acc = __builtin_amdgcn_mfma_f32_16x16x32_bf16(f, bfr[nt], zq, 0, 0, 0);
        GELU_ACC(acc[0], colacc[nt]); GELU_ACC(acc[1], colacc[nt]);
        GELU_ACC(acc[2], colacc[nt]); GELU_ACC(acc[3], colacc[nt]);
      }
    }
    if (rb < s1){
      int row = rb + m;
      int e = (row < s1) ? perm2d[base + row] : 0;
      short8 f;
      if (q < 2){
        const float4* ap = (const float4*)(ef + (size_t)e*16 + (q<<3));
        f = cvt8pk(ap[0], ap[1]);
      } else if (q == 2){
        f = zz; f[0] = (short)0x3F80; f[1] = (short)0x3F80;
      } else f = zz;
      const int vr = s1 - rb;
#pragma unroll
      for (int nt=0; nt<4; ++nt){
        f32x4 acc = __builtin_amdgcn_mfma_f32_16x16x32_bf16(f, bfr[nt], zq, 0, 0, 0);
        GELU_ACC_M(acc[0], colacc[nt], ((q<<2)+0) < vr);
        GELU_ACC_M(acc[1], colacc[nt], ((q<<2)+1) < vr);
        GELU_ACC_M(acc[2], colacc[nt], ((q<<2)+2) < vr);
        GELU_ACC_M(acc[3], colacc[nt], ((q<<2)+3) < vr);
      }
    }
#pragma unroll
    for (int nt=0; nt<4; ++nt){
      float s = colacc[nt];
      s += __shfl_xor(s, 16); s += __shfl_xor(s, 32);
      if (lane < 16){
        int o = (g << 10) + 512 + c0 + (nt<<4) + lane;
        unsigned short h = f2bf(s);
        Sh[o] = h; Sl[o] = f2bf(s - bf2f(h));
      }
    }
  } else {
    // ---------------- NODE: 2 blocks/graph, wave owns 64 cols ----------------
    const int b2 = blockIdx.x - 2048;
    const int g = b2 >> 1;
    const int c0 = ((b2 & 1) << 8) + (w << 6);
    short8 bf0[4], bf1[4]; float colacc[4] = {0.f,0.f,0.f,0.f};
#pragma unroll
    for (int nt=0; nt<4; ++nt){
      const unsigned short* bp = w1nT + ((c0 + (nt<<4) + m) << 6) + (q << 3);
      bf0[nt] = *(const short8*)bp;
      bf1[nt] = *(const short8*)(bp + 32);
    }
    const int s0 = nstart[g], s1 = nstart[g+1];
    const int nfull = (s1 - s0) >> 4;
    int rb = s0;
    for (int ch=0; ch<nfull; ++ch, rb += 16){
      int ar = rb + m;
      const float4* ap = (const float4*)(nf + (size_t)ar*32 + (q<<3));
      short8 f = cvt8pk(ap[0], ap[1]);
      int cls = ny[ar];
      short dpb = (short)f2bf(dp[ar]);
      short8 h = zz;
      if (q == 0){
#pragma unroll
        for (int j=0;j<8;++j) h[j] = (cls==j) ? dpb : (short)0;
      } else if (q == 1){
        h[1] = (short)0x3F80; h[2] = (short)0x3F80;   // k=41,42 -> bias hi+lo
        if (cls == 8) h[0] = dpb;
      }
#pragma unroll
      for (int nt=0; nt<4; ++nt){
        f32x4 acc = __builtin_amdgcn_mfma_f32_16x16x32_bf16(f, bf0[nt], zq, 0, 0, 0);
        acc = __builtin_amdgcn_mfma_f32_16x16x32_bf16(h, bf1[nt], acc, 0, 0, 0);
        GELU_ACC(acc[0], colacc[nt]); GELU_ACC(acc[1], colacc[nt]);
        GELU_ACC(acc[2], colacc[nt]); GELU_ACC(acc[3], colacc[nt]);
      }
    }
    if (rb < s1){
      int row = rb + m;
      int ar = (row < s1) ? row : s0;
      const float4* ap = (const float4*)(nf + (size_t)ar*32 + (q<<3));
      short8 f = cvt8pk(ap[0], ap[1]);
      int cls = ny[ar];
      short dpb = (short)f2bf(dp[ar]);
      short8 h = zz;
      if (q == 0){
#pragma unroll
        for (int j=0;j<8;++j) h[j] = (cls==j) ? dpb : (short)0;
      } else if (q == 1){
        h[1] = (short)0x3F80; h[2] = (short)0x3F80;
        if (cls == 8) h[0] = dpb;
      }
      const int vr = s1 - rb;
#pragma unroll
      for (int nt=0; nt<4; ++nt){
        f32x4 acc = __builtin_amdgcn_mfma_f32_16x16x32_bf16(f, bf0[nt], zq, 0, 0, 0);
        acc = __builtin_amdgcn_mfma_f32_16x16x32_bf16(h, bf1[nt], acc, 0, 0, 0);
        GELU_ACC_M(acc[0], colacc[nt], ((q<<2)+0) < vr);
        GELU_ACC_M(acc[1], colacc[nt], ((q<<2)+1) < vr);
        GELU_ACC_M(acc[2], colacc[nt], ((q<<2)+2) < vr);
        GELU_ACC_M(acc[3], colacc[nt], ((q<<2)+3) < vr);
      }
    }
#pragma unroll
    for (int nt=0; nt<4; ++nt){
      float s = colacc[nt];
      s += __shfl_xor(s, 16); s += __shfl_xor(s, 32);
      if (lane < 16){
        int o = (g << 10) + c0 + (nt<<4) + lane;
        unsigned short h = f2bf(s);
        Sh[o] = h; Sl[o] = f2bf(s - bf2f(h));
      }
    }
  }
}

// ========== pre-split bf16 hi/lo MFMA GEMM, A and B both pre-split (no runtime split8)
// mode: gf!=null -> G1 (out = acc + gf + cn*b2n + ce*b2e, bf16-plane store)
//       gf==null -> gelu(bn(...)): outf!=null -> f32 store, else bf16-plane store
__global__ __launch_bounds__(256) void kg2(
    const unsigned short* __restrict__ Ah, const unsigned short* __restrict__ Al,
    int K, int nkc,
    const unsigned short* __restrict__ Bh, const unsigned short* __restrict__ Bl,
    const float* __restrict__ gf, const int* __restrict__ nstart, const int* __restrict__ cnt,
    const float* __restrict__ b2n, const float* __restrict__ b2e,
    const float* __restrict__ bias, const float* __restrict__ gam, const float* __restrict__ bet,
    unsigned short* __restrict__ outh, unsigned short* __restrict__ outl,
    float* __restrict__ outf){
  const int t = threadIdx.x, lane = t & 63, w = t >> 6;
  const int q = lane >> 4, m = lane & 15;
  const int c0 = blockIdx.x * 16, r0 = blockIdx.y * 64 + w * 16;
  f32x4 acc = {0.f,0.f,0.f,0.f};
  const unsigned short* ahp = Ah + (size_t)(r0 + m) * K + (q << 3);
  const unsigned short* alp = Al + (size_t)(r0 + m) * K + (q << 3);
  const unsigned short* bhp = Bh + (size_t)(c0 + m) * K + (q << 3);
  const unsigned short* blp = Bl + (size_t)(c0 + m) * K + (q << 3);
  for (int kc = 0; kc < nkc; ++kc){
    const int ko = kc << 5;
    short8 ah = *(const short8*)(ahp + ko);
    short8 al = *(const short8*)(alp + ko);
    short8 bh = *(const short8*)(bhp + ko);
    short8 bl = *(const short8*)(blp + ko);
    acc = __builtin_amdgcn_mfma_f32_16x16x32_bf16(ah, bh, acc, 0, 0, 0);
    acc = __builtin_amdgcn_mfma_f32_16x16x32_bf16(al, bh, acc, 0, 0, 0);
    acc = __builtin_amdgcn_mfma_f32_16x16x32_bf16(ah, bl, acc, 0, 0, 0);
  }
  const float rs = 0.99999500003750f;
  const int c = c0 + m;
  if (gf){
    const float bn = b2n[c], be = b2e[c];
#pragma unroll
    for (int i=0;i<4;++i){
      int r = r0 + (q<<2) + i;
      float cn = (float)(nstart[r+1] - nstart[r]);
      float ce = (float)cnt[r];
      float v = acc[i] + gf[(size_t)r*HH + c] + cn*bn + ce*be;
      unsigned short h = f2bf(v);
      outh[(size_t)r*HH + c] = h;
      outl[(size_t)r*HH + c] = f2bf(v - bf2f(h));
    }
  } else {
    const float sc = gam[c]*rs, bi = bias[c], be = bet[c];
#pragma unroll
    for (int i=0;i<4;++i){
      int r = r0 + (q<<2) + i;
      float v = gelu_f((acc[i] + bi)*sc + be);
      if (outf) outf[(size_t)r*HH + c] = v;
      else {
        unsigned short h = f2bf(v);
        outh[(size_t)r*HH + c] = h;
        outl[(size_t)r*HH + c] = f2bf(v - bf2f(h));
      }
    }
  }
}

// ========== final 512 -> 2 linear ==========
__global__ __launch_bounds__(256) void kfinal(const float* __restrict__ x2, const float* __restrict__ w3,
    const float* __restrict__ b3, float* __restrict__ out){
  const int lane = threadIdx.x & 63, wv = threadIdx.x >> 6;
  const int r = blockIdx.x*4 + wv;
  float a0 = 0.f, a1 = 0.f;
#pragma unroll
  for (int tt=0; tt<8; ++tt){
    int k = lane + tt*64;
    float x = x2[(size_t)r*HH + k];
    a0 = __builtin_fmaf(x, w3[2*k], a0);
    a1 = __builtin_fmaf(x, w3[2*k+1], a1);
  }
#pragma unroll
  for (int d=1; d<64; d<<=1){ a0 += __shfl_xor(a0, d); a1 += __shfl_xor(a1, d); }
  if (lane == 0){ out[r*2] = a0 + b3[0]; out[r*2+1] = a1 + b3[1]; }
}

extern "C" void kernel_launch(void* const* d_in, const int* in_sizes, int n_in,
                              void* d_out, int out_size, void* d_ws, size_t ws_size,
                              hipStream_t stream) {
  const float* nf    = (const float*)d_in[0];
  const float* ef    = (const float*)d_in[1];
  const float* gf    = (const float*)d_in[2];
  const float* dp    = (const float*)d_in[3];
  const int*   ny    = (const int*)d_in[4];
  const int*   bidx  = (const int*)d_in[5];
  const int*   eidx  = (const int*)d_in[6];
  const float* nfw1  = (const float*)d_in[7];
  const float* nfb1  = (const float*)d_in[8];
  const float* nfg1  = (const float*)d_in[9];
  const float* nfbe1 = (const float*)d_in[10];
  const float* w2n   = (const float*)d_in[11];
  const float* b2n   = (const float*)d_in[12];
  const float* efw1  = (const float*)d_in[13];
  const float* efb1  = (const float*)d_in[14];
  const float* efg1  = (const float*)d_in[15];
  const float* efbe1 = (const float*)d_in[16];
  const float* w2e   = (const float*)d_in[17];
  const float* b2e   = (const float*)d_in[18];
  const float* ow1   = (const float*)d_in[19];
  const float* ob1   = (const float*)d_in[20];
  const float* og1   = (const float*)d_in[21];
  const float* obe1  = (const float*)d_in[22];
  const float* ow2   = (const float*)d_in[23];
  const float* ob2   = (const float*)d_in[24];
  const float* og2   = (const float*)d_in[25];
  const float* obe2  = (const float*)d_in[26];
  const float* ow3   = (const float*)d_in[27];
  const float* ob3   = (const float*)d_in[28];

  unsigned char* p = (unsigned char*)d_ws;
  unsigned short* Sh = (unsigned short*)p; p += (size_t)NG*1024*2;   // 2MB
  unsigned short* Sl = (unsigned short*)p; p += (size_t)NG*1024*2;   // 2MB
  int* perm2d = (int*)p;                   p += (size_t)NG*ECAP*4;   // 4MB (reused below)
  int* cnt    = (int*)p;                   p += NG*4;
  int* nstart = (int*)p;                   p += (NG+8)*4;
  unsigned short* w1nT = (unsigned short*)p; p += 512*64*2;
  unsigned short* w1eT = (unsigned short*)p; p += 512*32*2;
  unsigned short* Bh1 = (unsigned short*)p; p += (size_t)512*1024*2; // 1MB
  unsigned short* Bl1 = (unsigned short*)p; p += (size_t)512*1024*2; // 1MB
  unsigned short* Bh2 = (unsigned short*)p; p += 512*512*2;
  unsigned short* Bl2 = (unsigned short*)p; p += 512*512*2;
  unsigned short* Bh3 = (unsigned short*)p; p += 512*512*2;
  unsigned short* Bl3 = (unsigned short*)p; p += 512*512*2;
  float2* tab = (float2*)p;                p += 256*8;
  unsigned short* ghh = (unsigned short*)p; p += (size_t)NG*HH*2;    // 1MB
  unsigned short* ghl = (unsigned short*)p; p += (size_t)NG*HH*2;    // 1MB
  // aliases into perm2d region (dead after kmain): xg planes + final f32 activations
  unsigned short* xgh = (unsigned short*)perm2d;
  unsigned short* xgl = xgh + (size_t)NG*HH;
  float* x2f = (float*)(xgl + (size_t)NG*HH);

  kpre<<<6095, 256, 0, stream>>>(nfw1, nfb1, nfg1, nfbe1, efw1, efb1, efg1, efbe1,
                                 w2n, w2e, ow1, ow2, bidx, w1nT, w1eT,
                                 Bh1, Bl1, Bh2, Bl2, Bh3, Bl3, tab, cnt, nstart,
                                 (int4*)perm2d);
  kscatter<<<(NE+255)/256, 256, 0, stream>>>(eidx, bidx, cnt, perm2d);
  kmain<<<4096, 256, 0, stream>>>(nf, dp, ny, nstart, ef, perm2d, cnt, w1nT, w1eT,
                                  tab, Sh, Sl);
  // G1: gh = S @ [w2n;w2e] + gf + cn*b2n + ce*b2e   (gh-init fused into epilogue)
  kg2<<<dim3(32,16), 256, 0, stream>>>(Sh, Sl, 1024, 32, Bh1, Bl1,
                                       gf, nstart, cnt, b2n, b2e,
                                       nullptr, nullptr, nullptr, ghh, ghl, nullptr);
  // G2: xg = gelu(bn(gh @ ow1 + ob1))
  kg2<<<dim3(32,16), 256, 0, stream>>>(ghh, ghl, 512, 16, Bh2, Bl2,
                                       nullptr, nullptr, nullptr, nullptr, nullptr,
                                       ob1, og1, obe1, xgh, xgl, nullptr);
  // G3: x2f = gelu(bn(xg @ ow2 + ob2))
  kg2<<<dim3(32,16), 256, 0, stream>>>(xgh, xgl, 512, 16, Bh3, Bl3,
                                       nullptr, nullptr, nullptr, nullptr, nullptr,
                                       ob2, og2, obe2, nullptr, nullptr, x2f);
  kfinal<<<NG/4, 256, 0, stream>>>(x2f, ow3, ob3, (float*)d_out);
}

// Round 2
// 488.917 us; speedup vs baseline: 1.0390x; 1.0390x over previous
//
#include <hip/hip_runtime.h>
#include <hip/hip_bf16.h>

#define NN 200000
#define NE 600000
#define NG 1024
#define HH 512
#define ECAP 1024

typedef short short8 __attribute__((ext_vector_type(8)));
typedef float f32x4 __attribute__((ext_vector_type(4)));

__device__ __forceinline__ unsigned short f2bf(float f){
  unsigned u = __float_as_uint(f);
  u += 0x7fffu + ((u >> 16) & 1u);
  return (unsigned short)(u >> 16);
}
__device__ __forceinline__ float bf2f(unsigned short h){
  return __uint_as_float(((unsigned)h) << 16);
}

// packed f32x8 -> bf16x8 (RTNE)
__device__ __forceinline__ short8 cvt8pk(float4 a, float4 b){
  union { short8 s; __hip_bfloat162 h[4]; } u;
  u.h[0] = __float22bfloat162_rn(make_float2(a.x, a.y));
  u.h[1] = __float22bfloat162_rn(make_float2(a.z, a.w));
  u.h[2] = __float22bfloat162_rn(make_float2(b.x, b.y));
  u.h[3] = __float22bfloat162_rn(make_float2(b.z, b.w));
  return u.s;
}

// f32x8 -> bf16 hi + bf16 lo (split-precision) — used by kgemm3 only
__device__ __forceinline__ void split8(const float* v, short8* hi, short8* lo){
  union { short8 s; __hip_bfloat162 h[4]; unsigned u[4]; } H, L;
#pragma unroll
  for (int p=0;p<4;++p){
    float a = v[2*p], b = v[2*p+1];
    H.h[p] = __float22bfloat162_rn(make_float2(a, b));
    unsigned hu = H.u[p];
    L.h[p] = __float22bfloat162_rn(make_float2(a - __uint_as_float(hu << 16),
                                               b - __uint_as_float(hu & 0xffff0000u)));
  }
  *hi = H.s; *lo = L.s;
}

// analytic gelu (GEMM epilogues only — tiny element counts)
__device__ __forceinline__ float gelu_f(float x){
  float p = __builtin_fmaf(x*x, -0.10294325f, -2.3022085f);
  float e = __builtin_amdgcn_exp2f(x * p);
  return x * __builtin_amdgcn_rcpf(1.0f + e);
}

// ========== kpre: w1 prep(196) + nstart(782) + cnt zero(1) + perm2d zero(1024) ==========
__global__ __launch_bounds__(256) void kpre(
    const float* __restrict__ nfw1, const float* __restrict__ nfb1,
    const float* __restrict__ nfg1, const float* __restrict__ nfbe1,
    const float* __restrict__ efw1, const float* __restrict__ efb1,
    const float* __restrict__ efg1, const float* __restrict__ efbe1,
    unsigned short* __restrict__ w1nT, unsigned short* __restrict__ w1eT,
    float* __restrict__ b1n, float* __restrict__ b1e,
    const int* __restrict__ bidx, int* __restrict__ nstart,
    int* __restrict__ cnt, int4* __restrict__ pz){
  const float rs = 0.99999500003750f;   // 1/sqrt(1+1e-5)
  int b = blockIdx.x, t = threadIdx.x;
  if (b < 196){
    int tid = b*256 + t;
    if (tid < 512*64){
      int c = tid >> 6, k = tid & 63;
      float w = (k < 41) ? nfw1[k*HH + c] * nfg1[c] * rs : 0.0f;
      w1nT[tid] = f2bf(w);
    } else if (tid < 512*96){
      int u = tid - 512*64; int c = u >> 5, k = u & 31;
      float w = (k < 16) ? efw1[k*HH + c] * efg1[c] * rs : 0.0f;
      w1eT[u] = f2bf(w);
    } else if (tid < 512*96 + 512){
      int c = tid - 512*96;
      b1n[c] = nfb1[c]*nfg1[c]*rs + nfbe1[c];
    } else if (tid < 512*96 + 1024){
      int c = tid - (512*96 + 512);
      b1e[c] = efb1[c]*efg1[c]*rs + efbe1[c];
    }
  } else if (b < 978){
    int i = (b-196)*256 + t;
    if (i < NN){
      int g0 = bidx[i];
      int g1 = (i+1 < NN) ? bidx[i+1] : NG;
      for (int g = g0+1; g <= g1; ++g) nstart[g] = i+1;
      if (i == 0) for (int g = 0; g <= g0; ++g) nstart[g] = 0;
    }
  } else if (b == 978){
    cnt[t] = 0; cnt[t+256] = 0; cnt[t+512] = 0; cnt[t+768] = 0;
  } else {
    int idx = (b-979)*256 + t;                // zero perm2d (1M ints, int4 stores)
    pz[idx] = make_int4(0,0,0,0);
  }
}

// ========== kscatter: atomic-cursor bucket scatter ==========
__global__ __launch_bounds__(256) void kscatter(const int* __restrict__ eidx,
    const int* __restrict__ bidx, int* __restrict__ cnt, int* __restrict__ perm2d){
  int e = blockIdx.x*256 + threadIdx.x;
  if (e < NE){
    int g = bidx[eidx[e]];
    int p = atomicAdd(&cnt[g], 1);
    if (p < ECAP) perm2d[(g << 10) + p] = e;
  }
}

// ========== kghinit: gh = gf + cntn*b2n + cnte*b2e ==========
__global__ __launch_bounds__(256) void kghinit(const float* __restrict__ gf,
    const int* __restrict__ nstart, const int* __restrict__ cnt,
    const float* __restrict__ b2n, const float* __restrict__ b2e,
    float* __restrict__ gh){
  int i = blockIdx.x*256 + threadIdx.x;   // 131072 float4s
  int f = i*4;
  int r = f >> 9, c = f & 511;
  float cn = (float)(nstart[r+1] - nstart[r]);
  float ce = (float)cnt[r];
  float4 gv = *(const float4*)&gf[f];
  float4 bn4 = *(const float4*)&b2n[c];
  float4 be4 = *(const float4*)&b2e[c];
  float4 o;
  o.x = gv.x + cn*bn4.x + ce*be4.x;
  o.y = gv.y + cn*bn4.y + ce*be4.y;
  o.z = gv.z + cn*bn4.z + ce*be4.z;
  o.w = gv.w + cn*bn4.w + ce*be4.w;
  *(float4*)&gh[f] = o;
}

// gelu(x) = 0.5x + 0.5|x| - Q(|x|),  Q(v) = 0.5*v*erfc(v/sqrt2)
// Q via 64-entry per-lane register table + ds_bpermute (conflict-free crossbar, DS pipe)
#define GELU_ACC(x_, dst_) { \
  float ax_ = __builtin_fabsf(x_); \
  float tt_ = fminf(ax_ * 16.0f, 62.99f); \
  int ix_ = (int)tt_; \
  float fr_ = tt_ - (float)ix_; \
  int ad_ = ix_ << 2; \
  float tbv_ = __uint_as_float((unsigned)__builtin_amdgcn_ds_bpermute(ad_, (int)__float_as_uint(tb))); \
  float tsv_ = __uint_as_float((unsigned)__builtin_amdgcn_ds_bpermute(ad_, (int)__float_as_uint(ts))); \
  float Q_ = __builtin_fmaf(fr_, tsv_, tbv_); \
  float r_ = __builtin_fmaf(ax_, 0.5f, -Q_); \
  dst_ += __builtin_fmaf(x_, 0.5f, r_); }

#define GELU_ACC_M(x_, dst_, ok_) { \
  float ax_ = __builtin_fabsf(x_); \
  float tt_ = fminf(ax_ * 16.0f, 62.99f); \
  int ix_ = (int)tt_; \
  float fr_ = tt_ - (float)ix_; \
  int ad_ = ix_ << 2; \
  float tbv_ = __uint_as_float((unsigned)__builtin_amdgcn_ds_bpermute(ad_, (int)__float_as_uint(tb))); \
  float tsv_ = __uint_as_float((unsigned)__builtin_amdgcn_ds_bpermute(ad_, (int)__float_as_uint(ts))); \
  float Q_ = __builtin_fmaf(fr_, tsv_, tbv_); \
  float r_ = __builtin_fmaf(ax_, 0.5f, -Q_); \
  float g_ = __builtin_fmaf(x_, 0.5f, r_); \
  dst_ += (ok_) ? g_ : 0.0f; }

// ========== fused first layers (round-0 structure; gelu via bpermute LUT) ==========
__global__ __launch_bounds__(256) void kmain(
    const float* __restrict__ nf, const float* __restrict__ dp, const int* __restrict__ ny,
    const int* __restrict__ nstart, const float* __restrict__ ef,
    const int* __restrict__ perm2d, const int* __restrict__ cnt,
    const unsigned short* __restrict__ w1nT, const unsigned short* __restrict__ w1eT,
    const float* __restrict__ b1n, const float* __restrict__ b1e, float* __restrict__ S){
  const int t = threadIdx.x;
  const int lane = t & 63, w = t >> 6;
  const int q = lane >> 4, m = lane & 15;
  // per-lane LUT entry: lane l holds Q(l/16) and slope to Q((l+1)/16)
  float v0l = (float)lane * 0.0625f;
  float v1l = v0l + 0.0625f;
  float q0l = 0.5f * v0l * erfcf(v0l * 0.70710678118f);
  float q1l = 0.5f * v1l * erfcf(v1l * 0.70710678118f);
  const float tb = q0l, ts = q1l - q0l;
  const short8 zz = {0,0,0,0,0,0,0,0};
  if (blockIdx.x < 2048){
    // ---------------- EDGE ----------------
    const int g = blockIdx.x >> 1;
    const int c0 = ((blockIdx.x & 1) << 8) + (w << 6);
    short8 bfr[4]; float bias[4]; float colacc[4] = {0.f,0.f,0.f,0.f};
#pragma unroll
    for (int nt=0; nt<4; ++nt){
      int c = c0 + (nt<<4) + m;
      bfr[nt] = *(const short8*)(w1eT + (c << 5) + (q << 3));
      bias[nt] = b1e[c];
    }
    const int base = g << 10;
    const int s1 = cnt[g];
    const int nfull = s1 >> 4;
    int rb = 0;
    for (int ch=0; ch<nfull; ++ch, rb += 16){
      int e = perm2d[base + rb + m];
      short8 f = zz;
      if (q < 2){
        const float4* ap = (const float4*)(ef + (size_t)e*16 + (q<<3));
        f = cvt8pk(ap[0], ap[1]);
      }
#pragma unroll
      for (int nt=0; nt<4; ++nt){
        f32x4 acc = {bias[nt], bias[nt], bias[nt], bias[nt]};
        acc = __builtin_amdgcn_mfma_f32_16x16x32_bf16(f, bfr[nt], acc, 0, 0, 0);
        GELU_ACC(acc[0], colacc[nt]); GELU_ACC(acc[1], colacc[nt]);
        GELU_ACC(acc[2], colacc[nt]); GELU_ACC(acc[3], colacc[nt]);
      }
    }
    if (rb < s1){
      int row = rb + m;
      int e = perm2d[base + ((row < s1) ? row : 0)];
      short8 f = zz;
      if (q < 2){
        const float4* ap = (const float4*)(ef + (size_t)e*16 + (q<<3));
        f = cvt8pk(ap[0], ap[1]);
      }
      const int vr = s1 - rb;   // 1..15 valid rows in this chunk
#pragma unroll
      for (int nt=0; nt<4; ++nt){
        f32x4 acc = {bias[nt], bias[nt], bias[nt], bias[nt]};
        acc = __builtin_amdgcn_mfma_f32_16x16x32_bf16(f, bfr[nt], acc, 0, 0, 0);
        GELU_ACC_M(acc[0], colacc[nt], ((q<<2)+0) < vr);
        GELU_ACC_M(acc[1], colacc[nt], ((q<<2)+1) < vr);
        GELU_ACC_M(acc[2], colacc[nt], ((q<<2)+2) < vr);
        GELU_ACC_M(acc[3], colacc[nt], ((q<<2)+3) < vr);
      }
    }
#pragma unroll
    for (int nt=0; nt<4; ++nt){
      float s = colacc[nt];
      s += __shfl_xor(s, 16); s += __shfl_xor(s, 32);
      if (lane < 16) S[(size_t)g*1024 + 512 + c0 + (nt<<4) + lane] = s;
    }
  } else {
    // ---------------- NODE ----------------
    const int b2 = blockIdx.x - 2048;
    const int g = b2 >> 2;
    const int c0 = ((b2 & 3) << 7) + (w << 5);
    short8 bf0[2], bf1[2]; float bias[2]; float colacc[2] = {0.f,0.f};
#pragma unroll
    for (int nt=0; nt<2; ++nt){
      int c = c0 + (nt<<4) + m;
      const short8* bp = (const short8*)(w1nT + (c << 6) + (q << 3));
      bf0[nt] = bp[0]; bf1[nt] = bp[4];
      bias[nt] = b1n[c];
    }
    const int s0 = nstart[g], s1 = nstart[g+1];
    const int nfull = (s1 - s0) >> 4;
    int rb = s0;
    for (int ch=0; ch<nfull; ++ch, rb += 16){
      int ar = rb + m;
      const float4* ap = (const float4*)(nf + (size_t)ar*32 + (q<<3));
      short8 f = cvt8pk(ap[0], ap[1]);
      int cls = ny[ar];
      short dpb = (short)f2bf(dp[ar]);
      short8 h = zz;
      if (q == 0){
#pragma unroll
        for (int j=0;j<8;++j) h[j] = (cls==j) ? dpb : (short)0;
      } else if (q == 1 && cls == 8) h[0] = dpb;
#pragma unroll
      for (int nt=0; nt<2; ++nt){
        f32x4 acc = {bias[nt], bias[nt], bias[nt], bias[nt]};
        acc = __builtin_amdgcn_mfma_f32_16x16x32_bf16(f, bf0[nt], acc, 0, 0, 0);
        acc = __builtin_amdgcn_mfma_f32_16x16x32_bf16(h, bf1[nt], acc, 0, 0, 0);
        GELU_ACC(acc[0], colacc[nt]); GELU_ACC(acc[1], colacc[nt]);
        GELU_ACC(acc[2], colacc[nt]); GELU_ACC(acc[3], colacc[nt]);
      }
    }
    if (rb < s1){
      int row = rb + m;
      int ar = (row < s1) ? row : s0;
      const float4* ap = (const float4*)(nf + (size_t)ar*32 + (q<<3));
      short8 f = cvt8pk(ap[0], ap[1]);
      int cls = ny[ar];
      short dpb = (short)f2bf(dp[ar]);
      short8 h = zz;
      if (q == 0){
#pragma unroll
        for (int j=0;j<8;++j) h[j] = (cls==j) ? dpb : (short)0;
      } else if (q == 1 && cls == 8) h[0] = dpb;
      const int vr = s1 - rb;
#pragma unroll
      for (int nt=0; nt<2; ++nt){
        f32x4 acc = {bias[nt], bias[nt], bias[nt], bias[nt]};
        acc = __builtin_amdgcn_mfma_f32_16x16x32_bf16(f, bf0[nt], acc, 0, 0, 0);
        acc = __builtin_amdgcn_mfma_f32_16x16x32_bf16(h, bf1[nt], acc, 0, 0, 0);
        GELU_ACC_M(acc[0], colacc[nt], ((q<<2)+0) < vr);
        GELU_ACC_M(acc[1], colacc[nt], ((q<<2)+1) < vr);
        GELU_ACC_M(acc[2], colacc[nt], ((q<<2)+2) < vr);
        GELU_ACC_M(acc[3], colacc[nt], ((q<<2)+3) < vr);
      }
    }
#pragma unroll
    for (int nt=0; nt<2; ++nt){
      float s = colacc[nt];
      s += __shfl_xor(s, 16); s += __shfl_xor(s, 32);
      if (lane < 16) S[(size_t)g*1024 + c0 + (nt<<4) + lane] = s;
    }
  }
}

// ========== LDS-free bf16 split (hi+lo) MFMA GEMM, B direct from fp32 weights ==========
__global__ __launch_bounds__(256) void kgemm3(const float* __restrict__ A, int lda, int nkc,
    const float* __restrict__ B0, const float* __restrict__ B1,
    float* __restrict__ out, const float* __restrict__ pre, const float* __restrict__ bias,
    const float* __restrict__ gam, const float* __restrict__ bet){
  const int t = threadIdx.x, lane = t & 63, w = t >> 6;
  const int q = lane >> 4, m = lane & 15;
  const int c0 = blockIdx.x*32, r0 = blockIdx.y*64 + w*16;
  f32x4 acc[2] = {{0.f,0.f,0.f,0.f},{0.f,0.f,0.f,0.f}};
  const float* ap = A + (size_t)(r0 + m)*lda + (q<<3);
  for (int kc = 0; kc < nkc; ++kc){
    const int ko = kc*32;
    float4 x = *(const float4*)(ap + ko);
    float4 y = *(const float4*)(ap + ko + 4);
    float v[8] = {x.x,x.y,x.z,x.w,y.x,y.y,y.z,y.w};
    short8 ah, al;
    split8(v, &ah, &al);
    const float* Bp = (kc < 16) ? B0 : B1;
    const float* bp = Bp + (size_t)((kc & 15)*32 + (q<<3))*HH + c0 + m;
#pragma unroll
    for (int cf=0; cf<2; ++cf){
      float bv[8];
#pragma unroll
      for (int j=0;j<8;++j) bv[j] = bp[(size_t)j*HH + cf*16];
      short8 bh, bl;
      split8(bv, &bh, &bl);
      acc[cf] = __builtin_amdgcn_mfma_f32_16x16x32_bf16(ah, bh, acc[cf], 0, 0, 0);
      acc[cf] = __builtin_amdgcn_mfma_f32_16x16x32_bf16(ah, bl, acc[cf], 0, 0, 0);
      acc[cf] = __builtin_amdgcn_mfma_f32_16x16x32_bf16(al, bh, acc[cf], 0, 0, 0);
    }
  }
  const float rs = 0.99999500003750f;
#pragma unroll
  for (int cf=0; cf<2; ++cf){
    int c = c0 + cf*16 + m;
    float sc = 0.f, bi = 0.f, be = 0.f;
    if (!pre){ sc = gam[c]*rs; bi = bias[c]; be = bet[c]; }
#pragma unroll
    for (int i=0;i<4;++i){
      int r = blockIdx.y*64 + w*16 + q*4 + i;
      float vv = acc[cf][i];
      if (pre) vv += pre[(size_t)r*HH + c];
      else vv = gelu_f((vv + bi)*sc + be);
      out[(size_t)r*HH + c] = vv;
    }
  }
}

// ========== final 512 -> 2 linear ==========
__global__ __launch_bounds__(256) void kfinal(const float* __restrict__ x2, const float* __restrict__ w3,
    const float* __restrict__ b3, float* __restrict__ out){
  const int lane = threadIdx.x & 63, wv = threadIdx.x >> 6;
  const int r = blockIdx.x*4 + wv;
  float a0 = 0.f, a1 = 0.f;
#pragma unroll
  for (int tt=0; tt<8; ++tt){
    int k = lane + tt*64;
    float x = x2[(size_t)r*HH + k];
    a0 = __builtin_fmaf(x, w3[2*k], a0);
    a1 = __builtin_fmaf(x, w3[2*k+1], a1);
  }
#pragma unroll
  for (int d=1; d<64; d<<=1){ a0 += __shfl_xor(a0, d); a1 += __shfl_xor(a1, d); }
  if (lane == 0){ out[r*2] = a0 + b3[0]; out[r*2+1] = a1 + b3[1]; }
}

extern "C" void kernel_launch(void* const* d_in, const int* in_sizes, int n_in,
                              void* d_out, int out_size, void* d_ws, size_t ws_size,
                              hipStream_t stream) {
  const float* nf    = (const float*)d_in[0];
  const float* ef    = (const float*)d_in[1];
  const float* gf    = (const float*)d_in[2];
  const float* dp    = (const float*)d_in[3];
  const int*   ny    = (const int*)d_in[4];
  const int*   bidx  = (const int*)d_in[5];
  const int*   eidx  = (const int*)d_in[6];
  const float* nfw1  = (const float*)d_in[7];
  const float* nfb1  = (const float*)d_in[8];
  const float* nfg1  = (const float*)d_in[9];
  const float* nfbe1 = (const float*)d_in[10];
  const float* w2n   = (const float*)d_in[11];
  const float* b2n   = (const float*)d_in[12];
  const float* efw1  = (const float*)d_in[13];
  const float* efb1  = (const float*)d_in[14];
  const float* efg1  = (const float*)d_in[15];
  const float* efbe1 = (const float*)d_in[16];
  const float* w2e   = (const float*)d_in[17];
  const float* b2e   = (const float*)d_in[18];
  const float* ow1   = (const float*)d_in[19];
  const float* ob1   = (const float*)d_in[20];
  const float* og1   = (const float*)d_in[21];
  const float* obe1  = (const float*)d_in[22];
  const float* ow2   = (const float*)d_in[23];
  const float* ob2   = (const float*)d_in[24];
  const float* og2   = (const float*)d_in[25];
  const float* obe2  = (const float*)d_in[26];
  const float* ow3   = (const float*)d_in[27];
  const float* ob3   = (const float*)d_in[28];

  unsigned char* p = (unsigned char*)d_ws;
  float* S      = (float*)p;                 p += (size_t)NG*1024*4;  // 4MB
  int*   perm2d = (int*)p;                   p += (size_t)NG*ECAP*4;  // 4MB
  float* gh     = (float*)p;                 p += (size_t)NG*HH*4;    // 2MB
  float* xg2    = (float*)p;                 p += (size_t)NG*HH*4;    // 2MB
  float* x2f    = (float*)p;                 p += (size_t)NG*HH*4;    // 2MB
  unsigned short* w1nT = (unsigned short*)p; p += 512*64*2;
  unsigned short* w1eT = (unsigned short*)p; p += 512*32*2;
  float* b1n    = (float*)p;                 p += 512*4;
  float* b1e    = (float*)p;                 p += 512*4;
  int* nstart   = (int*)p;                   p += 1032*4;
  int* cnt      = (int*)p;                   p += NG*4;

  kpre<<<2003, 256, 0, stream>>>(nfw1, nfb1, nfg1, nfbe1, efw1, efb1, efg1, efbe1,
                                 w1nT, w1eT, b1n, b1e, bidx, nstart, cnt,
                                 (int4*)perm2d);
  kscatter<<<(NE+255)/256, 256, 0, stream>>>(eidx, bidx, cnt, perm2d);
  kghinit<<<512, 256, 0, stream>>>(gf, nstart, cnt, b2n, b2e, gh);
  kmain<<<6144, 256, 0, stream>>>(nf, dp, ny, nstart, ef, perm2d, cnt,
                                  w1nT, w1eT, b1n, b1e, S);
  // G1: gh = S @ [w2n;w2e] + gh_pre   (K=1024, in-place pre)
  kgemm3<<<dim3(16,16), 256, 0, stream>>>(S, 1024, 32, w2n, w2e, gh, gh,
                                          nullptr, nullptr, nullptr);
  // G2: xg2 = gelu(bn(gh @ ow1 + ob1))
  kgemm3<<<dim3(16,16), 256, 0, stream>>>(gh, 512, 16, ow1, ow1, xg2, nullptr,
                                          ob1, og1, obe1);
  // G3: x2f = gelu(bn(xg2 @ ow2 + ob2))
  kgemm3<<<dim3(16,16), 256, 0, stream>>>(xg2, 512, 16, ow2, ow2, x2f, nullptr,
                                          ob2, og2, obe2);
  kfinal<<<NG/4, 256, 0, stream>>>(x2f, ow3, ob3, (float*)d_out);
}

// Round 3
// 465.898 us; speedup vs baseline: 1.0903x; 1.0494x over previous
//
#include <hip/hip_runtime.h>
#include <hip/hip_bf16.h>

#define NN 200000
#define NE 600000
#define NG 1024
#define HH 512
#define ECAP 1024

typedef short short8 __attribute__((ext_vector_type(8)));
typedef float f32x4 __attribute__((ext_vector_type(4)));
typedef float f32x2 __attribute__((ext_vector_type(2)));

__device__ __forceinline__ unsigned short f2bf(float f){
  unsigned u = __float_as_uint(f);
  u += 0x7fffu + ((u >> 16) & 1u);
  return (unsigned short)(u >> 16);
}
__device__ __forceinline__ float bf2f(unsigned short h){
  return __uint_as_float(((unsigned)h) << 16);
}

// packed f32x8 -> bf16x8 (RTNE)
__device__ __forceinline__ short8 cvt8pk(float4 a, float4 b){
  union { short8 s; __hip_bfloat162 h[4]; } u;
  u.h[0] = __float22bfloat162_rn(make_float2(a.x, a.y));
  u.h[1] = __float22bfloat162_rn(make_float2(a.z, a.w));
  u.h[2] = __float22bfloat162_rn(make_float2(b.x, b.y));
  u.h[3] = __float22bfloat162_rn(make_float2(b.z, b.w));
  return u.s;
}

// f32x8 -> bf16 hi + bf16 lo (split-precision) — kgemm3 only
__device__ __forceinline__ void split8(const float* v, short8* hi, short8* lo){
  union { short8 s; __hip_bfloat162 h[4]; unsigned u[4]; } H, L;
#pragma unroll
  for (int p=0;p<4;++p){
    float a = v[2*p], b = v[2*p+1];
    H.h[p] = __float22bfloat162_rn(make_float2(a, b));
    unsigned hu = H.u[p];
    L.h[p] = __float22bfloat162_rn(make_float2(a - __uint_as_float(hu << 16),
                                               b - __uint_as_float(hu & 0xffff0000u)));
  }
  *hi = H.s; *lo = L.s;
}

// analytic gelu (GEMM epilogues only — 1M elements total)
__device__ __forceinline__ float gelu_f(float x){
  float p = __builtin_fmaf(x*x, -0.10294325f, -2.3022085f);
  float e = __builtin_amdgcn_exp2f(x * p);
  return x * __builtin_amdgcn_rcpf(1.0f + e);
}

// scalar even-poly gelu: gelu(x) = 0.5x + P(s), s = x^2/8 - 1  (tail path)
__device__ __forceinline__ float gelu_poly(float x,
    float C0, float C1, float C2, float C3, float C4, float C5, float C6, float C7){
  float u = x*x;
  float s = __builtin_fmaf(u, 0.125f, -1.0f);
  float p = C7;
  p = __builtin_fmaf(p, s, C6); p = __builtin_fmaf(p, s, C5);
  p = __builtin_fmaf(p, s, C4); p = __builtin_fmaf(p, s, C3);
  p = __builtin_fmaf(p, s, C2); p = __builtin_fmaf(p, s, C1);
  p = __builtin_fmaf(p, s, C0);
  return __builtin_fmaf(x, 0.5f, p);
}

// packed (float2 -> v_pk_*) gelu-accumulate: dst += gelu(x) elementwise
__device__ __forceinline__ void gelu2_acc(f32x2 x, f32x2& dst,
    float C0, float C1, float C2, float C3, float C4, float C5, float C6, float C7){
  f32x2 u = x*x;
  f32x2 s = __builtin_elementwise_fma(u, (f32x2)0.125f, (f32x2)(-1.0f));
  f32x2 p = (f32x2)C7;
  p = __builtin_elementwise_fma(p, s, (f32x2)C6);
  p = __builtin_elementwise_fma(p, s, (f32x2)C5);
  p = __builtin_elementwise_fma(p, s, (f32x2)C4);
  p = __builtin_elementwise_fma(p, s, (f32x2)C3);
  p = __builtin_elementwise_fma(p, s, (f32x2)C2);
  p = __builtin_elementwise_fma(p, s, (f32x2)C1);
  p = __builtin_elementwise_fma(p, s, (f32x2)C0);
  dst += __builtin_elementwise_fma(x, (f32x2)0.5f, p);
}

// ========== kpre: w1 prep(196) + nstart(782) + cnt zero(1) + gelu poly fit(1) ==========
__global__ __launch_bounds__(256) void kpre(
    const float* __restrict__ nfw1, const float* __restrict__ nfb1,
    const float* __restrict__ nfg1, const float* __restrict__ nfbe1,
    const float* __restrict__ efw1, const float* __restrict__ efb1,
    const float* __restrict__ efg1, const float* __restrict__ efbe1,
    unsigned short* __restrict__ w1nT, unsigned short* __restrict__ w1eT,
    float* __restrict__ b1n, float* __restrict__ b1e,
    const int* __restrict__ bidx, int* __restrict__ nstart,
    int* __restrict__ cnt, float* __restrict__ pcoef){
  const float rs = 0.99999500003750f;   // 1/sqrt(1+1e-5)
  int b = blockIdx.x, t = threadIdx.x;
  if (b < 196){
    int tid = b*256 + t;
    if (tid < 512*64){
      int c = tid >> 6, k = tid & 63;
      float w = (k < 41) ? nfw1[k*HH + c] * nfg1[c] * rs : 0.0f;
      w1nT[tid] = f2bf(w);
    } else if (tid < 512*96){
      int u = tid - 512*64; int c = u >> 5, k = u & 31;
      float w = (k < 16) ? efw1[k*HH + c] * efg1[c] * rs : 0.0f;
      w1eT[u] = f2bf(w);
    } else if (tid < 512*96 + 512){
      int c = tid - 512*96;
      b1n[c] = nfb1[c]*nfg1[c]*rs + nfbe1[c];
    } else if (tid < 512*96 + 1024){
      int c = tid - (512*96 + 512);
      b1e[c] = efb1[c]*efg1[c]*rs + efbe1[c];
    }
  } else if (b < 978){
    int i = (b-196)*256 + t;
    if (i < NN){
      int g0 = bidx[i];
      int g1 = (i+1 < NN) ? bidx[i+1] : NG;
      for (int g = g0+1; g <= g1; ++g) nstart[g] = i+1;
      if (i == 0) for (int g = 0; g <= g0; ++g) nstart[g] = 0;
    }
  } else if (b == 978){
    cnt[t] = 0; cnt[t+256] = 0; cnt[t+512] = 0; cnt[t+768] = 0;
  } else {
    // b == 979: deg-7 Chebyshev interpolant of E(u)=0.5*sqrt(u)*erf(sqrt(u/2)),
    // u in [0,16], s = u/8 - 1. Double precision; forced P(-1)=0 so gelu(0)=0.
    if (t == 0){
      double th[8], fj[8];
      for (int j=0;j<8;++j){
        th[j] = 3.14159265358979323846*((double)j + 0.5)/8.0;
        double cs = cos(th[j]);
        double u = 8.0*(cs + 1.0);
        double v = sqrt(u);
        fj[j] = 0.5*v*erf(v*0.70710678118654752);
      }
      double c[8];
      for (int k=0;k<8;++k){
        double sm = 0.0;
        for (int j=0;j<8;++j) sm += fj[j]*cos((double)k*th[j]);
        c[k] = 0.25*sm;   // 2/8
      }
      c[0] *= 0.5;
      const double T[8][8] = {
        { 1, 0,  0,  0,   0,    0,  0,  0},
        { 0, 1,  0,  0,   0,    0,  0,  0},
        {-1, 0,  2,  0,   0,    0,  0,  0},
        { 0,-3,  0,  4,   0,    0,  0,  0},
        { 1, 0, -8,  0,   8,    0,  0,  0},
        { 0, 5,  0,-20,   0,   16,  0,  0},
        {-1, 0, 18,  0, -48,    0, 32,  0},
        { 0,-7,  0, 56,   0, -112,  0, 64}};
      double m[8] = {0,0,0,0,0,0,0,0};
      for (int k=0;k<8;++k)
        for (int i=0;i<8;++i) m[i] += c[k]*T[k][i];
      double p0 = m[0]-m[1]+m[2]-m[3]+m[4]-m[5]+m[6]-m[7];
      m[0] -= p0;
      for (int i=0;i<8;++i) pcoef[i] = (float)m[i];
    }
  }
}

// ========== kscatter: atomic-cursor bucket scatter ==========
__global__ __launch_bounds__(256) void kscatter(const int* __restrict__ eidx,
    const int* __restrict__ bidx, int* __restrict__ cnt, int* __restrict__ perm2d){
  int e = blockIdx.x*256 + threadIdx.x;
  if (e < NE){
    int g = bidx[eidx[e]];
    int p = atomicAdd(&cnt[g], 1);
    if (p < ECAP) perm2d[(g << 10) + p] = e;
  }
}

// ========== fused first layers (round-0 structure; packed-poly gelu) ==========
__global__ __launch_bounds__(256) void kmain(
    const float* __restrict__ nf, const float* __restrict__ dp, const int* __restrict__ ny,
    const int* __restrict__ nstart, const float* __restrict__ ef,
    const int* __restrict__ perm2d, const int* __restrict__ cnt,
    const unsigned short* __restrict__ w1nT, const unsigned short* __restrict__ w1eT,
    const float* __restrict__ b1n, const float* __restrict__ b1e,
    const float* __restrict__ pcoef, float* __restrict__ S){
  const int t = threadIdx.x;
  const int lane = t & 63, w = t >> 6;
  const int q = lane >> 4, m = lane & 15;
  const float C0 = pcoef[0], C1 = pcoef[1], C2 = pcoef[2], C3 = pcoef[3];
  const float C4 = pcoef[4], C5 = pcoef[5], C6 = pcoef[6], C7 = pcoef[7];
  const short8 zz = {0,0,0,0,0,0,0,0};
  if (blockIdx.x < 2048){
    // ---------------- EDGE ----------------
    const int g = blockIdx.x >> 1;
    const int c0 = ((blockIdx.x & 1) << 8) + (w << 6);
    short8 bfr[4]; float bias[4];
    f32x2 cacc[4] = {{0.f,0.f},{0.f,0.f},{0.f,0.f},{0.f,0.f}};
#pragma unroll
    for (int nt=0; nt<4; ++nt){
      int c = c0 + (nt<<4) + m;
      bfr[nt] = *(const short8*)(w1eT + (c << 5) + (q << 3));
      bias[nt] = b1e[c];
    }
    const int base = g << 10;
    const int s1 = cnt[g];
    const int nfull = s1 >> 4;
    int rb = 0;
    for (int ch=0; ch<nfull; ++ch, rb += 16){
      int e = perm2d[base + rb + m];
      short8 f = zz;
      if (q < 2){
        const float4* ap = (const float4*)(ef + (size_t)e*16 + (q<<3));
        f = cvt8pk(ap[0], ap[1]);
      }
#pragma unroll
      for (int nt=0; nt<4; ++nt){
        f32x4 acc = {bias[nt], bias[nt], bias[nt], bias[nt]};
        acc = __builtin_amdgcn_mfma_f32_16x16x32_bf16(f, bfr[nt], acc, 0, 0, 0);
        f32x2 xlo = {acc[0], acc[1]}, xhi = {acc[2], acc[3]};
        gelu2_acc(xlo, cacc[nt], C0,C1,C2,C3,C4,C5,C6,C7);
        gelu2_acc(xhi, cacc[nt], C0,C1,C2,C3,C4,C5,C6,C7);
      }
    }
    if (rb < s1){
      int row = rb + m;
      int e = perm2d[base + ((row < s1) ? row : 0)];
      short8 f = zz;
      if (q < 2){
        const float4* ap = (const float4*)(ef + (size_t)e*16 + (q<<3));
        f = cvt8pk(ap[0], ap[1]);
      }
      const int vr = s1 - rb;   // 1..15 valid rows
#pragma unroll
      for (int nt=0; nt<4; ++nt){
        f32x4 acc = {bias[nt], bias[nt], bias[nt], bias[nt]};
        acc = __builtin_amdgcn_mfma_f32_16x16x32_bf16(f, bfr[nt], acc, 0, 0, 0);
#pragma unroll
        for (int i=0;i<4;++i){
          float gv = (((q<<2)+i) < vr) ? gelu_poly(acc[i], C0,C1,C2,C3,C4,C5,C6,C7) : 0.f;
          cacc[nt].x += gv;
        }
      }
    }
#pragma unroll
    for (int nt=0; nt<4; ++nt){
      float s = cacc[nt].x + cacc[nt].y;
      s += __shfl_xor(s, 16); s += __shfl_xor(s, 32);
      if (lane < 16) S[(size_t)g*1024 + 512 + c0 + (nt<<4) + lane] = s;
    }
  } else {
    // ---------------- NODE ----------------
    const int b2 = blockIdx.x - 2048;
    const int g = b2 >> 2;
    const int c0 = ((b2 & 3) << 7) + (w << 5);
    short8 bf0[2], bf1[2]; float bias[2];
    f32x2 cacc[2] = {{0.f,0.f},{0.f,0.f}};
#pragma unroll
    for (int nt=0; nt<2; ++nt){
      int c = c0 + (nt<<4) + m;
      const short8* bp = (const short8*)(w1nT + (c << 6) + (q << 3));
      bf0[nt] = bp[0]; bf1[nt] = bp[4];
      bias[nt] = b1n[c];
    }
    const int s0 = nstart[g], s1 = nstart[g+1];
    const int nfull = (s1 - s0) >> 4;
    int rb = s0;
    for (int ch=0; ch<nfull; ++ch, rb += 16){
      int ar = rb + m;
      const float4* ap = (const float4*)(nf + (size_t)ar*32 + (q<<3));
      short8 f = cvt8pk(ap[0], ap[1]);
      int cls = ny[ar];
      short dpb = (short)f2bf(dp[ar]);
      short8 h = zz;
      if (q == 0){
#pragma unroll
        for (int j=0;j<8;++j) h[j] = (cls==j) ? dpb : (short)0;
      } else if (q == 1 && cls == 8) h[0] = dpb;
#pragma unroll
      for (int nt=0; nt<2; ++nt){
        f32x4 acc = {bias[nt], bias[nt], bias[nt], bias[nt]};
        acc = __builtin_amdgcn_mfma_f32_16x16x32_bf16(f, bf0[nt], acc, 0, 0, 0);
        acc = __builtin_amdgcn_mfma_f32_16x16x32_bf16(h, bf1[nt], acc, 0, 0, 0);
        f32x2 xlo = {acc[0], acc[1]}, xhi = {acc[2], acc[3]};
        gelu2_acc(xlo, cacc[nt], C0,C1,C2,C3,C4,C5,C6,C7);
        gelu2_acc(xhi, cacc[nt], C0,C1,C2,C3,C4,C5,C6,C7);
      }
    }
    if (rb < s1){
      int row = rb + m;
      int ar = (row < s1) ? row : s0;
      const float4* ap = (const float4*)(nf + (size_t)ar*32 + (q<<3));
      short8 f = cvt8pk(ap[0], ap[1]);
      int cls = ny[ar];
      short dpb = (short)f2bf(dp[ar]);
      short8 h = zz;
      if (q == 0){
#pragma unroll
        for (int j=0;j<8;++j) h[j] = (cls==j) ? dpb : (short)0;
      } else if (q == 1 && cls == 8) h[0] = dpb;
      const int vr = s1 - rb;
#pragma unroll
      for (int nt=0; nt<2; ++nt){
        f32x4 acc = {bias[nt], bias[nt], bias[nt], bias[nt]};
        acc = __builtin_amdgcn_mfma_f32_16x16x32_bf16(f, bf0[nt], acc, 0, 0, 0);
        acc = __builtin_amdgcn_mfma_f32_16x16x32_bf16(h, bf1[nt], acc, 0, 0, 0);
#pragma unroll
        for (int i=0;i<4;++i){
          float gv = (((q<<2)+i) < vr) ? gelu_poly(acc[i], C0,C1,C2,C3,C4,C5,C6,C7) : 0.f;
          cacc[nt].x += gv;
        }
      }
    }
#pragma unroll
    for (int nt=0; nt<2; ++nt){
      float s = cacc[nt].x + cacc[nt].y;
      s += __shfl_xor(s, 16); s += __shfl_xor(s, 32);
      if (lane < 16) S[(size_t)g*1024 + c0 + (nt<<4) + lane] = s;
    }
  }
}

// ========== LDS-free bf16 split (hi+lo) MFMA GEMM, B direct from fp32 weights ==========
// G1 mode (gf!=null): out = acc + gf + cn*b2n + ce*b2e   (gh-init fused)
// else: out = gelu(bn(acc + bias))
__global__ __launch_bounds__(256) void kgemm3(const float* __restrict__ A, int lda, int nkc,
    const float* __restrict__ B0, const float* __restrict__ B1,
    float* __restrict__ out,
    const float* __restrict__ gf, const int* __restrict__ nstart, const int* __restrict__ cnt,
    const float* __restrict__ b2n, const float* __restrict__ b2e,
    const float* __restrict__ bias, const float* __restrict__ gam, const float* __restrict__ bet){
  const int t = threadIdx.x, lane = t & 63, w = t >> 6;
  const int q = lane >> 4, m = lane & 15;
  const int c0 = blockIdx.x*32, r0 = blockIdx.y*64 + w*16;
  f32x4 acc[2] = {{0.f,0.f,0.f,0.f},{0.f,0.f,0.f,0.f}};
  const float* ap = A + (size_t)(r0 + m)*lda + (q<<3);
  for (int kc = 0; kc < nkc; ++kc){
    const int ko = kc*32;
    float4 x = *(const float4*)(ap + ko);
    float4 y = *(const float4*)(ap + ko + 4);
    float v[8] = {x.x,x.y,x.z,x.w,y.x,y.y,y.z,y.w};
    short8 ah, al;
    split8(v, &ah, &al);
    const float* Bp = (kc < 16) ? B0 : B1;
    const float* bp = Bp + (size_t)((kc & 15)*32 + (q<<3))*HH + c0 + m;
#pragma unroll
    for (int cf=0; cf<2; ++cf){
      float bv[8];
#pragma unroll
      for (int j=0;j<8;++j) bv[j] = bp[(size_t)j*HH + cf*16];
      short8 bh, bl;
      split8(bv, &bh, &bl);
      acc[cf] = __builtin_amdgcn_mfma_f32_16x16x32_bf16(ah, bh, acc[cf], 0, 0, 0);
      acc[cf] = __builtin_amdgcn_mfma_f32_16x16x32_bf16(ah, bl, acc[cf], 0, 0, 0);
      acc[cf] = __builtin_amdgcn_mfma_f32_16x16x32_bf16(al, bh, acc[cf], 0, 0, 0);
    }
  }
  const float rs = 0.99999500003750f;
#pragma unroll
  for (int cf=0; cf<2; ++cf){
    int c = c0 + cf*16 + m;
    if (gf){
      const float bnv = b2n[c], bev = b2e[c];
#pragma unroll
      for (int i=0;i<4;++i){
        int r = blockIdx.y*64 + w*16 + q*4 + i;
        float cn = (float)(nstart[r+1] - nstart[r]);
        float ce = (float)cnt[r];
        float vv = acc[cf][i] + gf[(size_t)r*HH + c] + cn*bnv + ce*bev;
        out[(size_t)r*HH + c] = vv;
      }
    } else {
      const float sc = gam[c]*rs, bi = bias[c], be = bet[c];
#pragma unroll
      for (int i=0;i<4;++i){
        int r = blockIdx.y*64 + w*16 + q*4 + i;
        float vv = gelu_f((acc[cf][i] + bi)*sc + be);
        out[(size_t)r*HH + c] = vv;
      }
    }
  }
}

// ========== final 512 -> 2 linear ==========
__global__ __launch_bounds__(256) void kfinal(const float* __restrict__ x2, const float* __restrict__ w3,
    const float* __restrict__ b3, float* __restrict__ out){
  const int lane = threadIdx.x & 63, wv = threadIdx.x >> 6;
  const int r = blockIdx.x*4 + wv;
  float a0 = 0.f, a1 = 0.f;
#pragma unroll
  for (int tt=0; tt<8; ++tt){
    int k = lane + tt*64;
    float x = x2[(size_t)r*HH + k];
    a0 = __builtin_fmaf(x, w3[2*k], a0);
    a1 = __builtin_fmaf(x, w3[2*k+1], a1);
  }
#pragma unroll
  for (int d=1; d<64; d<<=1){ a0 += __shfl_xor(a0, d); a1 += __shfl_xor(a1, d); }
  if (lane == 0){ out[r*2] = a0 + b3[0]; out[r*2+1] = a1 + b3[1]; }
}

extern "C" void kernel_launch(void* const* d_in, const int* in_sizes, int n_in,
                              void* d_out, int out_size, void* d_ws, size_t ws_size,
                              hipStream_t stream) {
  const float* nf    = (const float*)d_in[0];
  const float* ef    = (const float*)d_in[1];
  const float* gf    = (const float*)d_in[2];
  const float* dp    = (const float*)d_in[3];
  const int*   ny    = (const int*)d_in[4];
  const int*   bidx  = (const int*)d_in[5];
  const int*   eidx  = (const int*)d_in[6];
  const float* nfw1  = (const float*)d_in[7];
  const float* nfb1  = (const float*)d_in[8];
  const float* nfg1  = (const float*)d_in[9];
  const float* nfbe1 = (const float*)d_in[10];
  const float* w2n   = (const float*)d_in[11];
  const float* b2n   = (const float*)d_in[12];
  const float* efw1  = (const float*)d_in[13];
  const float* efb1  = (const float*)d_in[14];
  const float* efg1  = (const float*)d_in[15];
  const float* efbe1 = (const float*)d_in[16];
  const float* w2e   = (const float*)d_in[17];
  const float* b2e   = (const float*)d_in[18];
  const float* ow1   = (const float*)d_in[19];
  const float* ob1   = (const float*)d_in[20];
  const float* og1   = (const float*)d_in[21];
  const float* obe1  = (const float*)d_in[22];
  const float* ow2   = (const float*)d_in[23];
  const float* ob2   = (const float*)d_in[24];
  const float* og2   = (const float*)d_in[25];
  const float* obe2  = (const float*)d_in[26];
  const float* ow3   = (const float*)d_in[27];
  const float* ob3   = (const float*)d_in[28];

  unsigned char* p = (unsigned char*)d_ws;
  float* S      = (float*)p;                 p += (size_t)NG*1024*4;  // 4MB
  int*   perm2d = (int*)p;                   p += (size_t)NG*ECAP*4;  // 4MB
  float* gh     = (float*)p;                 p += (size_t)NG*HH*4;    // 2MB
  float* xg2    = (float*)p;                 p += (size_t)NG*HH*4;    // 2MB
  float* x2f    = (float*)p;                 p += (size_t)NG*HH*4;    // 2MB
  unsigned short* w1nT = (unsigned short*)p; p += 512*64*2;
  unsigned short* w1eT = (unsigned short*)p; p += 512*32*2;
  float* b1n    = (float*)p;                 p += 512*4;
  float* b1e    = (float*)p;                 p += 512*4;
  int* nstart   = (int*)p;                   p += 1032*4;
  int* cnt      = (int*)p;                   p += NG*4;
  float* pcoef  = (float*)p;                 p += 64;

  kpre<<<980, 256, 0, stream>>>(nfw1, nfb1, nfg1, nfbe1, efw1, efb1, efg1, efbe1,
                                w1nT, w1eT, b1n, b1e, bidx, nstart, cnt, pcoef);
  kscatter<<<(NE+255)/256, 256, 0, stream>>>(eidx, bidx, cnt, perm2d);
  kmain<<<6144, 256, 0, stream>>>(nf, dp, ny, nstart, ef, perm2d, cnt,
                                  w1nT, w1eT, b1n, b1e, pcoef, S);
  // G1: gh = S @ [w2n;w2e] + gf + cn*b2n + ce*b2e   (gh-init fused into epilogue)
  kgemm3<<<dim3(16,16), 256, 0, stream>>>(S, 1024, 32, w2n, w2e, gh,
                                          gf, nstart, cnt, b2n, b2e,
                                          nullptr, nullptr, nullptr);
  // G2: xg2 = gelu(bn(gh @ ow1 + ob1))
  kgemm3<<<dim3(16,16), 256, 0, stream>>>(gh, 512, 16, ow1, ow1, xg2,
                                          nullptr, nullptr, nullptr, nullptr, nullptr,
                                          ob1, og1, obe1);
  // G3: x2f = gelu(bn(xg2 @ ow2 + ob2))
  kgemm3<<<dim3(16,16), 256, 0, stream>>>(xg2, 512, 16, ow2, ow2, x2f,
                                          nullptr, nullptr, nullptr, nullptr, nullptr,
                                          ob2, og2, obe2);
  kfinal<<<NG/4, 256, 0, stream>>>(x2f, ow3, ob3, (float*)d_out);
}

// Round 4
// 350.027 us; speedup vs baseline: 1.4512x; 1.3310x over previous
//
#include <hip/hip_runtime.h>
#include <hip/hip_bf16.h>

#define NN 200000
#define NE 600000
#define NG 1024
#define HH 512
#define ECAP 1024

typedef short short8 __attribute__((ext_vector_type(8)));
typedef float f32x4 __attribute__((ext_vector_type(4)));
typedef float f32x2 __attribute__((ext_vector_type(2)));

__device__ __forceinline__ unsigned short f2bf(float f){
  unsigned u = __float_as_uint(f);
  u += 0x7fffu + ((u >> 16) & 1u);
  return (unsigned short)(u >> 16);
}
__device__ __forceinline__ float bf2f(unsigned short h){
  return __uint_as_float(((unsigned)h) << 16);
}

// packed f32x8 -> bf16x8 (RTNE)
__device__ __forceinline__ short8 cvt8pk(float4 a, float4 b){
  union { short8 s; __hip_bfloat162 h[4]; } u;
  u.h[0] = __float22bfloat162_rn(make_float2(a.x, a.y));
  u.h[1] = __float22bfloat162_rn(make_float2(a.z, a.w));
  u.h[2] = __float22bfloat162_rn(make_float2(b.x, b.y));
  u.h[3] = __float22bfloat162_rn(make_float2(b.z, b.w));
  return u.s;
}

// f32x8 -> bf16 hi + bf16 lo (split-precision) — kgemm3 only
__device__ __forceinline__ void split8(const float* v, short8* hi, short8* lo){
  union { short8 s; __hip_bfloat162 h[4]; unsigned u[4]; } H, L;
#pragma unroll
  for (int p=0;p<4;++p){
    float a = v[2*p], b = v[2*p+1];
    H.h[p] = __float22bfloat162_rn(make_float2(a, b));
    unsigned hu = H.u[p];
    L.h[p] = __float22bfloat162_rn(make_float2(a - __uint_as_float(hu << 16),
                                               b - __uint_as_float(hu & 0xffff0000u)));
  }
  *hi = H.s; *lo = L.s;
}

// analytic gelu (GEMM epilogues only — 1M elements total)
__device__ __forceinline__ float gelu_f(float x){
  float p = __builtin_fmaf(x*x, -0.10294325f, -2.3022085f);
  float e = __builtin_amdgcn_exp2f(x * p);
  return x * __builtin_amdgcn_rcpf(1.0f + e);
}

// scalar even-poly gelu: gelu(x) = 0.5x + P(s), s = x^2/8 - 1  (tail path)
__device__ __forceinline__ float gelu_poly(float x,
    float C0, float C1, float C2, float C3, float C4, float C5, float C6, float C7){
  float u = x*x;
  float s = __builtin_fmaf(u, 0.125f, -1.0f);
  float p = C7;
  p = __builtin_fmaf(p, s, C6); p = __builtin_fmaf(p, s, C5);
  p = __builtin_fmaf(p, s, C4); p = __builtin_fmaf(p, s, C3);
  p = __builtin_fmaf(p, s, C2); p = __builtin_fmaf(p, s, C1);
  p = __builtin_fmaf(p, s, C0);
  return __builtin_fmaf(x, 0.5f, p);
}

// packed (float2 -> v_pk_*) gelu-accumulate: dst += gelu(x) elementwise
__device__ __forceinline__ void gelu2_acc(f32x2 x, f32x2& dst,
    float C0, float C1, float C2, float C3, float C4, float C5, float C6, float C7){
  f32x2 u = x*x;
  f32x2 s = __builtin_elementwise_fma(u, (f32x2)0.125f, (f32x2)(-1.0f));
  f32x2 p = (f32x2)C7;
  p = __builtin_elementwise_fma(p, s, (f32x2)C6);
  p = __builtin_elementwise_fma(p, s, (f32x2)C5);
  p = __builtin_elementwise_fma(p, s, (f32x2)C4);
  p = __builtin_elementwise_fma(p, s, (f32x2)C3);
  p = __builtin_elementwise_fma(p, s, (f32x2)C2);
  p = __builtin_elementwise_fma(p, s, (f32x2)C1);
  p = __builtin_elementwise_fma(p, s, (f32x2)C0);
  dst += __builtin_elementwise_fma(x, (f32x2)0.5f, p);
}

// ========== kpre: w1 prep(196) + nstart(782) + cnt zero + poly fit + node prepack(782) ==
__global__ __launch_bounds__(256) void kpre(
    const float* __restrict__ nfw1, const float* __restrict__ nfb1,
    const float* __restrict__ nfg1, const float* __restrict__ nfbe1,
    const float* __restrict__ efw1, const float* __restrict__ efb1,
    const float* __restrict__ efg1, const float* __restrict__ efbe1,
    unsigned short* __restrict__ w1nT, unsigned short* __restrict__ w1eT,
    float* __restrict__ b1n, float* __restrict__ b1e,
    const int* __restrict__ bidx, int* __restrict__ nstart,
    int* __restrict__ cnt, float* __restrict__ pcoef,
    const float* __restrict__ nf, const float* __restrict__ dp,
    const int* __restrict__ ny,
    unsigned short* __restrict__ nfb, unsigned short* __restrict__ hb){
  const float rs = 0.99999500003750f;   // 1/sqrt(1+1e-5)
  int b = blockIdx.x, t = threadIdx.x;
  if (b < 196){
    int tid = b*256 + t;
    if (tid < 512*64){
      int c = tid >> 6, k = tid & 63;
      float w = (k < 41) ? nfw1[k*HH + c] * nfg1[c] * rs : 0.0f;
      w1nT[tid] = f2bf(w);
    } else if (tid < 512*96){
      int u = tid - 512*64; int c = u >> 5, k = u & 31;
      float w = (k < 16) ? efw1[k*HH + c] * efg1[c] * rs : 0.0f;
      w1eT[u] = f2bf(w);
    } else if (tid < 512*96 + 512){
      int c = tid - 512*96;
      b1n[c] = nfb1[c]*nfg1[c]*rs + nfbe1[c];
    } else if (tid < 512*96 + 1024){
      int c = tid - (512*96 + 512);
      b1e[c] = efb1[c]*efg1[c]*rs + efbe1[c];
    }
  } else if (b < 978){
    int i = (b-196)*256 + t;
    if (i < NN){
      int g0 = bidx[i];
      int g1 = (i+1 < NN) ? bidx[i+1] : NG;
      for (int g = g0+1; g <= g1; ++g) nstart[g] = i+1;
      if (i == 0) for (int g = 0; g <= g0; ++g) nstart[g] = 0;
    }
  } else if (b == 978){
    cnt[t] = 0; cnt[t+256] = 0; cnt[t+512] = 0; cnt[t+768] = 0;
  } else if (b == 979){
    // deg-7 Chebyshev interpolant of E(u)=0.5*sqrt(u)*erf(sqrt(u/2)),
    // u in [0,16], s = u/8 - 1. Double precision; forced P(-1)=0 so gelu(0)=0.
    if (t == 0){
      double th[8], fj[8];
      for (int j=0;j<8;++j){
        th[j] = 3.14159265358979323846*((double)j + 0.5)/8.0;
        double cs = cos(th[j]);
        double u = 8.0*(cs + 1.0);
        double v = sqrt(u);
        fj[j] = 0.5*v*erf(v*0.70710678118654752);
      }
      double c[8];
      for (int k=0;k<8;++k){
        double sm = 0.0;
        for (int j=0;j<8;++j) sm += fj[j]*cos((double)k*th[j]);
        c[k] = 0.25*sm;
      }
      c[0] *= 0.5;
      const double T[8][8] = {
        { 1, 0,  0,  0,   0,    0,  0,  0},
        { 0, 1,  0,  0,   0,    0,  0,  0},
        {-1, 0,  2,  0,   0,    0,  0,  0},
        { 0,-3,  0,  4,   0,    0,  0,  0},
        { 1, 0, -8,  0,   8,    0,  0,  0},
        { 0, 5,  0,-20,   0,   16,  0,  0},
        {-1, 0, 18,  0, -48,    0, 32,  0},
        { 0,-7,  0, 56,   0, -112,  0, 64}};
      double m[8] = {0,0,0,0,0,0,0,0};
      for (int k=0;k<8;++k)
        for (int i=0;i<8;++i) m[i] += c[k]*T[k][i];
      double p0 = m[0]-m[1]+m[2]-m[3]+m[4]-m[5]+m[6]-m[7];
      m[0] -= p0;
      for (int i=0;i<8;++i) pcoef[i] = (float)m[i];
    }
  } else {
    // node prepack: nfb[r] = bf16x32 of nf row; hb[r] = bf16x16 one-hot(ny)*dp
    int r = (b-980)*256 + t;
    if (r < NN){
      const float4* ap = (const float4*)(nf + (size_t)r*32);
      unsigned short* op = nfb + (size_t)r*32;
#pragma unroll
      for (int p2=0; p2<4; ++p2){
        short8 s = cvt8pk(ap[2*p2], ap[2*p2+1]);
        *(short8*)(op + 8*p2) = s;
      }
      unsigned short db = f2bf(dp[r]);
      int cls = ny[r];
      short8 h0, h1;
#pragma unroll
      for (int j=0;j<8;++j) h0[j] = (cls==j) ? (short)db : (short)0;
      h1 = (short8){0,0,0,0,0,0,0,0};
      h1[0] = (cls==8) ? (short)db : (short)0;
      unsigned short* hp = hb + (size_t)r*16;
      *(short8*)hp = h0;
      *(short8*)(hp + 8) = h1;
    }
  }
}

// ========== kscatter: two-level scatter (LDS histogram + one global atomic per (blk,g)) ==
__global__ __launch_bounds__(1024) void kscatter(const int* __restrict__ eidx,
    const int* __restrict__ bidx, int* __restrict__ eg,
    int* __restrict__ cnt, int* __restrict__ perm2d){
  __shared__ int h[NG];
  __shared__ int base[NG];
  const int b = blockIdx.x, t = threadIdx.x;
  h[t] = 0;
  __syncthreads();
  const int per = NE / 64;            // 9375, exact
  const int lo = b*per, hi = lo + per;
  for (int e = lo + t; e < hi; e += 1024){
    int g = bidx[eidx[e]];
    eg[e] = g;
    atomicAdd(&h[g], 1);
  }
  __syncthreads();
  int c = h[t];
  if (c > 0) base[t] = atomicAdd(&cnt[t], c);
  h[t] = 0;
  __syncthreads();
  for (int e = lo + t; e < hi; e += 1024){
    int g = eg[e];
    int p = base[g] + atomicAdd(&h[g], 1);
    perm2d[(g << 10) + p] = e;
  }
}

// ========== fused first layers (packed-poly gelu; prepacked node inputs) ==========
__global__ __launch_bounds__(256) void kmain(
    const unsigned short* __restrict__ nfb, const unsigned short* __restrict__ hb,
    const int* __restrict__ nstart, const float* __restrict__ ef,
    const int* __restrict__ perm2d, const int* __restrict__ cnt,
    const unsigned short* __restrict__ w1nT, const unsigned short* __restrict__ w1eT,
    const float* __restrict__ b1n, const float* __restrict__ b1e,
    const float* __restrict__ pcoef, float* __restrict__ S){
  const int t = threadIdx.x;
  const int lane = t & 63, w = t >> 6;
  const int q = lane >> 4, m = lane & 15;
  const float C0 = pcoef[0], C1 = pcoef[1], C2 = pcoef[2], C3 = pcoef[3];
  const float C4 = pcoef[4], C5 = pcoef[5], C6 = pcoef[6], C7 = pcoef[7];
  const short8 zz = {0,0,0,0,0,0,0,0};
  if (blockIdx.x < 2048){
    // ---------------- EDGE ----------------
    const int g = blockIdx.x >> 1;
    const int c0 = ((blockIdx.x & 1) << 8) + (w << 6);
    short8 bfr[4]; float bias[4];
    f32x2 cacc[4] = {{0.f,0.f},{0.f,0.f},{0.f,0.f},{0.f,0.f}};
#pragma unroll
    for (int nt=0; nt<4; ++nt){
      int c = c0 + (nt<<4) + m;
      bfr[nt] = *(const short8*)(w1eT + (c << 5) + (q << 3));
      bias[nt] = b1e[c];
    }
    const int base = g << 10;
    const int s1 = cnt[g];
    const int nfull = s1 >> 4;
    int rb = 0;
    for (int ch=0; ch<nfull; ++ch, rb += 16){
      int e = perm2d[base + rb + m];
      short8 f = zz;
      if (q < 2){
        const float4* ap = (const float4*)(ef + (size_t)e*16 + (q<<3));
        f = cvt8pk(ap[0], ap[1]);
      }
#pragma unroll
      for (int nt=0; nt<4; ++nt){
        f32x4 acc = {bias[nt], bias[nt], bias[nt], bias[nt]};
        acc = __builtin_amdgcn_mfma_f32_16x16x32_bf16(f, bfr[nt], acc, 0, 0, 0);
        f32x2 xlo = {acc[0], acc[1]}, xhi = {acc[2], acc[3]};
        gelu2_acc(xlo, cacc[nt], C0,C1,C2,C3,C4,C5,C6,C7);
        gelu2_acc(xhi, cacc[nt], C0,C1,C2,C3,C4,C5,C6,C7);
      }
    }
    if (rb < s1){
      int row = rb + m;
      int e = perm2d[base + ((row < s1) ? row : 0)];
      short8 f = zz;
      if (q < 2){
        const float4* ap = (const float4*)(ef + (size_t)e*16 + (q<<3));
        f = cvt8pk(ap[0], ap[1]);
      }
      const int vr = s1 - rb;   // 1..15 valid rows
#pragma unroll
      for (int nt=0; nt<4; ++nt){
        f32x4 acc = {bias[nt], bias[nt], bias[nt], bias[nt]};
        acc = __builtin_amdgcn_mfma_f32_16x16x32_bf16(f, bfr[nt], acc, 0, 0, 0);
#pragma unroll
        for (int i=0;i<4;++i){
          float gv = (((q<<2)+i) < vr) ? gelu_poly(acc[i], C0,C1,C2,C3,C4,C5,C6,C7) : 0.f;
          cacc[nt].x += gv;
        }
      }
    }
#pragma unroll
    for (int nt=0; nt<4; ++nt){
      float s = cacc[nt].x + cacc[nt].y;
      s += __shfl_xor(s, 16); s += __shfl_xor(s, 32);
      if (lane < 16) S[(size_t)g*1024 + 512 + c0 + (nt<<4) + lane] = s;
    }
  } else {
    // ---------------- NODE (prepacked bf16 inputs) ----------------
    const int b2 = blockIdx.x - 2048;
    const int g = b2 >> 2;
    const int c0 = ((b2 & 3) << 7) + (w << 5);
    short8 bf0[2], bf1[2]; float bias[2];
    f32x2 cacc[2] = {{0.f,0.f},{0.f,0.f}};
#pragma unroll
    for (int nt=0; nt<2; ++nt){
      int c = c0 + (nt<<4) + m;
      const short8* bp = (const short8*)(w1nT + (c << 6) + (q << 3));
      bf0[nt] = bp[0]; bf1[nt] = bp[4];
      bias[nt] = b1n[c];
    }
    const int s0 = nstart[g], s1 = nstart[g+1];
    const int nfull = (s1 - s0) >> 4;
    int rb = s0;
    for (int ch=0; ch<nfull; ++ch, rb += 16){
      int ar = rb + m;
      short8 f = *(const short8*)(nfb + (size_t)ar*32 + (q<<3));
      short8 h = (q < 2) ? *(const short8*)(hb + (size_t)ar*16 + (q<<3)) : zz;
#pragma unroll
      for (int nt=0; nt<2; ++nt){
        f32x4 acc = {bias[nt], bias[nt], bias[nt], bias[nt]};
        acc = __builtin_amdgcn_mfma_f32_16x16x32_bf16(f, bf0[nt], acc, 0, 0, 0);
        acc = __builtin_amdgcn_mfma_f32_16x16x32_bf16(h, bf1[nt], acc, 0, 0, 0);
        f32x2 xlo = {acc[0], acc[1]}, xhi = {acc[2], acc[3]};
        gelu2_acc(xlo, cacc[nt], C0,C1,C2,C3,C4,C5,C6,C7);
        gelu2_acc(xhi, cacc[nt], C0,C1,C2,C3,C4,C5,C6,C7);
      }
    }
    if (rb < s1){
      int row = rb + m;
      int ar = (row < s1) ? row : s0;
      short8 f = *(const short8*)(nfb + (size_t)ar*32 + (q<<3));
      short8 h = (q < 2) ? *(const short8*)(hb + (size_t)ar*16 + (q<<3)) : zz;
      const int vr = s1 - rb;
#pragma unroll
      for (int nt=0; nt<2; ++nt){
        f32x4 acc = {bias[nt], bias[nt], bias[nt], bias[nt]};
        acc = __builtin_amdgcn_mfma_f32_16x16x32_bf16(f, bf0[nt], acc, 0, 0, 0);
        acc = __builtin_amdgcn_mfma_f32_16x16x32_bf16(h, bf1[nt], acc, 0, 0, 0);
#pragma unroll
        for (int i=0;i<4;++i){
          float gv = (((q<<2)+i) < vr) ? gelu_poly(acc[i], C0,C1,C2,C3,C4,C5,C6,C7) : 0.f;
          cacc[nt].x += gv;
        }
      }
    }
#pragma unroll
    for (int nt=0; nt<2; ++nt){
      float s = cacc[nt].x + cacc[nt].y;
      s += __shfl_xor(s, 16); s += __shfl_xor(s, 32);
      if (lane < 16) S[(size_t)g*1024 + c0 + (nt<<4) + lane] = s;
    }
  }
}

// ========== LDS-free bf16 split (hi+lo) MFMA GEMM, B direct from fp32 weights ==========
// G1 mode (gf!=null): out = acc + gf + cn*b2n + ce*b2e   (gh-init fused)
// else: out = gelu(bn(acc + bias))
__global__ __launch_bounds__(256) void kgemm3(const float* __restrict__ A, int lda, int nkc,
    const float* __restrict__ B0, const float* __restrict__ B1,
    float* __restrict__ out,
    const float* __restrict__ gf, const int* __restrict__ nstart, const int* __restrict__ cnt,
    const float* __restrict__ b2n, const float* __restrict__ b2e,
    const float* __restrict__ bias, const float* __restrict__ gam, const float* __restrict__ bet){
  const int t = threadIdx.x, lane = t & 63, w = t >> 6;
  const int q = lane >> 4, m = lane & 15;
  const int c0 = blockIdx.x*32, r0 = blockIdx.y*64 + w*16;
  f32x4 acc[2] = {{0.f,0.f,0.f,0.f},{0.f,0.f,0.f,0.f}};
  const float* ap = A + (size_t)(r0 + m)*lda + (q<<3);
  for (int kc = 0; kc < nkc; ++kc){
    const int ko = kc*32;
    float4 x = *(const float4*)(ap + ko);
    float4 y = *(const float4*)(ap + ko + 4);
    float v[8] = {x.x,x.y,x.z,x.w,y.x,y.y,y.z,y.w};
    short8 ah, al;
    split8(v, &ah, &al);
    const float* Bp = (kc < 16) ? B0 : B1;
    const float* bp = Bp + (size_t)((kc & 15)*32 + (q<<3))*HH + c0 + m;
#pragma unroll
    for (int cf=0; cf<2; ++cf){
      float bv[8];
#pragma unroll
      for (int j=0;j<8;++j) bv[j] = bp[(size_t)j*HH + cf*16];
      short8 bh, bl;
      split8(bv, &bh, &bl);
      acc[cf] = __builtin_amdgcn_mfma_f32_16x16x32_bf16(ah, bh, acc[cf], 0, 0, 0);
      acc[cf] = __builtin_amdgcn_mfma_f32_16x16x32_bf16(ah, bl, acc[cf], 0, 0, 0);
      acc[cf] = __builtin_amdgcn_mfma_f32_16x16x32_bf16(al, bh, acc[cf], 0, 0, 0);
    }
  }
  const float rs = 0.99999500003750f;
#pragma unroll
  for (int cf=0; cf<2; ++cf){
    int c = c0 + cf*16 + m;
    if (gf){
      const float bnv = b2n[c], bev = b2e[c];
#pragma unroll
      for (int i=0;i<4;++i){
        int r = blockIdx.y*64 + w*16 + q*4 + i;
        float cn = (float)(nstart[r+1] - nstart[r]);
        float ce = (float)cnt[r];
        float vv = acc[cf][i] + gf[(size_t)r*HH + c] + cn*bnv + ce*bev;
        out[(size_t)r*HH + c] = vv;
      }
    } else {
      const float sc = gam[c]*rs, bi = bias[c], be = bet[c];
#pragma unroll
      for (int i=0;i<4;++i){
        int r = blockIdx.y*64 + w*16 + q*4 + i;
        float vv = gelu_f((acc[cf][i] + bi)*sc + be);
        out[(size_t)r*HH + c] = vv;
      }
    }
  }
}

// ========== final 512 -> 2 linear ==========
__global__ __launch_bounds__(256) void kfinal(const float* __restrict__ x2, const float* __restrict__ w3,
    const float* __restrict__ b3, float* __restrict__ out){
  const int lane = threadIdx.x & 63, wv = threadIdx.x >> 6;
  const int r = blockIdx.x*4 + wv;
  float a0 = 0.f, a1 = 0.f;
#pragma unroll
  for (int tt=0; tt<8; ++tt){
    int k = lane + tt*64;
    float x = x2[(size_t)r*HH + k];
    a0 = __builtin_fmaf(x, w3[2*k], a0);
    a1 = __builtin_fmaf(x, w3[2*k+1], a1);
  }
#pragma unroll
  for (int d=1; d<64; d<<=1){ a0 += __shfl_xor(a0, d); a1 += __shfl_xor(a1, d); }
  if (lane == 0){ out[r*2] = a0 + b3[0]; out[r*2+1] = a1 + b3[1]; }
}

extern "C" void kernel_launch(void* const* d_in, const int* in_sizes, int n_in,
                              void* d_out, int out_size, void* d_ws, size_t ws_size,
                              hipStream_t stream) {
  const float* nf    = (const float*)d_in[0];
  const float* ef    = (const float*)d_in[1];
  const float* gf    = (const float*)d_in[2];
  const float* dp    = (const float*)d_in[3];
  const int*   ny    = (const int*)d_in[4];
  const int*   bidx  = (const int*)d_in[5];
  const int*   eidx  = (const int*)d_in[6];
  const float* nfw1  = (const float*)d_in[7];
  const float* nfb1  = (const float*)d_in[8];
  const float* nfg1  = (const float*)d_in[9];
  const float* nfbe1 = (const float*)d_in[10];
  const float* w2n   = (const float*)d_in[11];
  const float* b2n   = (const float*)d_in[12];
  const float* efw1  = (const float*)d_in[13];
  const float* efb1  = (const float*)d_in[14];
  const float* efg1  = (const float*)d_in[15];
  const float* efbe1 = (const float*)d_in[16];
  const float* w2e   = (const float*)d_in[17];
  const float* b2e   = (const float*)d_in[18];
  const float* ow1   = (const float*)d_in[19];
  const float* ob1   = (const float*)d_in[20];
  const float* og1   = (const float*)d_in[21];
  const float* obe1  = (const float*)d_in[22];
  const float* ow2   = (const float*)d_in[23];
  const float* ob2   = (const float*)d_in[24];
  const float* og2   = (const float*)d_in[25];
  const float* obe2  = (const float*)d_in[26];
  const float* ow3   = (const float*)d_in[27];
  const float* ob3   = (const float*)d_in[28];

  unsigned char* p = (unsigned char*)d_ws;
  float* S      = (float*)p;                 p += (size_t)NG*1024*4;  // 4MB
  int*   perm2d = (int*)p;                   p += (size_t)NG*ECAP*4;  // 4MB
  int*   eg     = (int*)p;                   p += (size_t)NE*4;       // 2.4MB
  unsigned short* nfb = (unsigned short*)p;  p += (size_t)NN*32*2;    // 12.8MB (reused)
  unsigned short* hb  = (unsigned short*)p;  p += (size_t)NN*16*2;    // 6.4MB
  unsigned short* w1nT = (unsigned short*)p; p += 512*64*2;
  unsigned short* w1eT = (unsigned short*)p; p += 512*32*2;
  float* b1n    = (float*)p;                 p += 512*4;
  float* b1e    = (float*)p;                 p += 512*4;
  int* nstart   = (int*)p;                   p += 1032*4;
  int* cnt      = (int*)p;                   p += NG*4;
  float* pcoef  = (float*)p;                 p += 64;
  // gh/xg2/x2f alias into nfb region (nfb dead after kmain; 6MB < 12.8MB)
  float* gh  = (float*)nfb;
  float* xg2 = gh  + (size_t)NG*HH;
  float* x2f = xg2 + (size_t)NG*HH;

  kpre<<<1762, 256, 0, stream>>>(nfw1, nfb1, nfg1, nfbe1, efw1, efb1, efg1, efbe1,
                                 w1nT, w1eT, b1n, b1e, bidx, nstart, cnt, pcoef,
                                 nf, dp, ny, nfb, hb);
  kscatter<<<64, 1024, 0, stream>>>(eidx, bidx, eg, cnt, perm2d);
  kmain<<<6144, 256, 0, stream>>>(nfb, hb, nstart, ef, perm2d, cnt,
                                  w1nT, w1eT, b1n, b1e, pcoef, S);
  // G1: gh = S @ [w2n;w2e] + gf + cn*b2n + ce*b2e   (gh-init fused into epilogue)
  kgemm3<<<dim3(16,16), 256, 0, stream>>>(S, 1024, 32, w2n, w2e, gh,
                                          gf, nstart, cnt, b2n, b2e,
                                          nullptr, nullptr, nullptr);
  // G2: xg2 = gelu(bn(gh @ ow1 + ob1))
  kgemm3<<<dim3(16,16), 256, 0, stream>>>(gh, 512, 16, ow1, ow1, xg2,
                                          nullptr, nullptr, nullptr, nullptr, nullptr,
                                          ob1, og1, obe1);
  // G3: x2f = gelu(bn(xg2 @ ow2 + ob2))
  kgemm3<<<dim3(16,16), 256, 0, stream>>>(xg2, 512, 16, ow2, ow2, x2f,
                                          nullptr, nullptr, nullptr, nullptr, nullptr,
                                          ob2, og2, obe2);
  kfinal<<<NG/4, 256, 0, stream>>>(x2f, ow3, ob3, (float*)d_out);
}

// Round 5
// 341.089 us; speedup vs baseline: 1.4892x; 1.0262x over previous
//
#include <hip/hip_runtime.h>
#include <hip/hip_bf16.h>

#define NN 200000
#define NE 600000
#define NG 1024
#define HH 512
#define ECAP 1024

typedef short short8 __attribute__((ext_vector_type(8)));
typedef float f32x4 __attribute__((ext_vector_type(4)));
typedef float f32x2 __attribute__((ext_vector_type(2)));
typedef float f32x16 __attribute__((ext_vector_type(16)));

__device__ __forceinline__ unsigned short f2bf(float f){
  unsigned u = __float_as_uint(f);
  u += 0x7fffu + ((u >> 16) & 1u);
  return (unsigned short)(u >> 16);
}
__device__ __forceinline__ float bf2f(unsigned short h){
  return __uint_as_float(((unsigned)h) << 16);
}

// packed f32x8 -> bf16x8 (RTNE)
__device__ __forceinline__ short8 cvt8pk(float4 a, float4 b){
  union { short8 s; __hip_bfloat162 h[4]; } u;
  u.h[0] = __float22bfloat162_rn(make_float2(a.x, a.y));
  u.h[1] = __float22bfloat162_rn(make_float2(a.z, a.w));
  u.h[2] = __float22bfloat162_rn(make_float2(b.x, b.y));
  u.h[3] = __float22bfloat162_rn(make_float2(b.z, b.w));
  return u.s;
}

// f32x8 -> bf16 hi + bf16 lo (split-precision) — kgemm3 only
__device__ __forceinline__ void split8(const float* v, short8* hi, short8* lo){
  union { short8 s; __hip_bfloat162 h[4]; unsigned u[4]; } H, L;
#pragma unroll
  for (int p=0;p<4;++p){
    float a = v[2*p], b = v[2*p+1];
    H.h[p] = __float22bfloat162_rn(make_float2(a, b));
    unsigned hu = H.u[p];
    L.h[p] = __float22bfloat162_rn(make_float2(a - __uint_as_float(hu << 16),
                                               b - __uint_as_float(hu & 0xffff0000u)));
  }
  *hi = H.s; *lo = L.s;
}

// analytic gelu (GEMM epilogues only — 1M elements total)
__device__ __forceinline__ float gelu_f(float x){
  float p = __builtin_fmaf(x*x, -0.10294325f, -2.3022085f);
  float e = __builtin_amdgcn_exp2f(x * p);
  return x * __builtin_amdgcn_rcpf(1.0f + e);
}

// packed gelu accumulate on PRE-SCALED input x' = x/(2*sqrt2):
//   s = x'^2 - 1  (in [-1,1] for |x|<=4);  P(s) = E(x^2);  P(-1)=0
//   aX += x'; aP += P(s).  Final: sum gelu = sqrt2*aX + aP
__device__ __forceinline__ void g2(f32x2 xp, f32x2& aX, f32x2& aP,
    float C0, float C1, float C2, float C3, float C4, float C5, float C6, float C7){
  f32x2 s = __builtin_elementwise_fma(xp, xp, (f32x2)(-1.0f));
  f32x2 p = __builtin_elementwise_fma(s, (f32x2)C7, (f32x2)C6);
  p = __builtin_elementwise_fma(p, s, (f32x2)C5);
  p = __builtin_elementwise_fma(p, s, (f32x2)C4);
  p = __builtin_elementwise_fma(p, s, (f32x2)C3);
  p = __builtin_elementwise_fma(p, s, (f32x2)C2);
  p = __builtin_elementwise_fma(p, s, (f32x2)C1);
  p = __builtin_elementwise_fma(p, s, (f32x2)C0);
  aX += xp; aP += p;
}

#define ISQ 0.35355339059327376f   // 1/(2*sqrt(2))
#define SQ2 1.41421356237309505f

// ========== kpre ==========
// b<2: w1eT16[col][16] + b1e_s ; b<4: w1n48T[col][48] + b1n_s ; b<786: nstart ;
// b==786: cnt zero + poly fit ; b<1569: nf48 prepack ; else: efb prepack
__global__ __launch_bounds__(256) void kpre(
    const float* __restrict__ nfw1, const float* __restrict__ nfb1,
    const float* __restrict__ nfg1, const float* __restrict__ nfbe1,
    const float* __restrict__ efw1, const float* __restrict__ efb1,
    const float* __restrict__ efg1, const float* __restrict__ efbe1,
    unsigned short* __restrict__ w1n48T, unsigned short* __restrict__ w1eT16,
    float* __restrict__ b1n_s, float* __restrict__ b1e_s,
    const int* __restrict__ bidx, int* __restrict__ nstart,
    int* __restrict__ cnt, float* __restrict__ pcoef,
    const float* __restrict__ nf, const float* __restrict__ dp,
    const int* __restrict__ ny, const float* __restrict__ ef,
    unsigned short* __restrict__ nf48, unsigned short* __restrict__ efb){
  const float rs = 0.99999500003750f;   // 1/sqrt(1+1e-5)
  int b = blockIdx.x, t = threadIdx.x;
  if (b < 2){
    int c = b*256 + t;
    float sc = efg1[c]*rs*ISQ;
#pragma unroll
    for (int k=0;k<16;++k) w1eT16[c*16+k] = f2bf(efw1[k*HH+c]*sc);
    b1e_s[c] = (efb1[c]*efg1[c]*rs + efbe1[c])*ISQ;
  } else if (b < 4){
    int c = (b-2)*256 + t;
    float sc = nfg1[c]*rs*ISQ;
#pragma unroll
    for (int k=0;k<48;++k)
      w1n48T[c*48+k] = (k < 41) ? f2bf(nfw1[k*HH+c]*sc) : (unsigned short)0;
    b1n_s[c] = (nfb1[c]*nfg1[c]*rs + nfbe1[c])*ISQ;
  } else if (b < 786){
    int i = (b-4)*256 + t;
    if (i < NN){
      int g0 = bidx[i];
      int g1 = (i+1 < NN) ? bidx[i+1] : NG;
      for (int g = g0+1; g <= g1; ++g) nstart[g] = i+1;
      if (i == 0) for (int g = 0; g <= g0; ++g) nstart[g] = 0;
    }
  } else if (b == 786){
    cnt[t] = 0; cnt[t+256] = 0; cnt[t+512] = 0; cnt[t+768] = 0;
    // deg-7 Chebyshev of E(u)=0.5*sqrt(u)*erf(sqrt(u/2)), u in [0,16], s=u/8-1,
    // P(-1) forced to 0. (identical to round-3/4 — validated)
    if (t == 0){
      double th[8], fj[8];
      for (int j=0;j<8;++j){
        th[j] = 3.14159265358979323846*((double)j + 0.5)/8.0;
        double cs = cos(th[j]);
        double u = 8.0*(cs + 1.0);
        double v = sqrt(u);
        fj[j] = 0.5*v*erf(v*0.70710678118654752);
      }
      double c[8];
      for (int k=0;k<8;++k){
        double sm = 0.0;
        for (int j=0;j<8;++j) sm += fj[j]*cos((double)k*th[j]);
        c[k] = 0.25*sm;
      }
      c[0] *= 0.5;
      const double T[8][8] = {
        { 1, 0,  0,  0,   0,    0,  0,  0},
        { 0, 1,  0,  0,   0,    0,  0,  0},
        {-1, 0,  2,  0,   0,    0,  0,  0},
        { 0,-3,  0,  4,   0,    0,  0,  0},
        { 1, 0, -8,  0,   8,    0,  0,  0},
        { 0, 5,  0,-20,   0,   16,  0,  0},
        {-1, 0, 18,  0, -48,    0, 32,  0},
        { 0,-7,  0, 56,   0, -112,  0, 64}};
      double m[8] = {0,0,0,0,0,0,0,0};
      for (int k=0;k<8;++k)
        for (int i=0;i<8;++i) m[i] += c[k]*T[k][i];
      double p0 = m[0]-m[1]+m[2]-m[3]+m[4]-m[5]+m[6]-m[7];
      m[0] -= p0;
      for (int i=0;i<8;++i) pcoef[i] = (float)m[i];
    }
  } else if (b < 1569){
    // nf48: [0..31]=nf, [32..40]=onehot(ny)*dp, [41..47]=0
    int r = (b-787)*256 + t;
    if (r < NN){
      const float4* ap = (const float4*)(nf + (size_t)r*32);
      unsigned short v[48];
      union { short8 s; unsigned short u[8]; } cv;
#pragma unroll
      for (int p2=0; p2<4; ++p2){
        cv.s = cvt8pk(ap[2*p2], ap[2*p2+1]);
#pragma unroll
        for (int j=0;j<8;++j) v[p2*8+j] = cv.u[j];
      }
      unsigned short db = f2bf(dp[r]);
      int cls = ny[r];
#pragma unroll
      for (int j=0;j<9;++j) v[32+j] = (cls==j) ? db : (unsigned short)0;
#pragma unroll
      for (int j=41;j<48;++j) v[j] = 0;
      unsigned short* op = nf48 + (size_t)r*48;
#pragma unroll
      for (int p2=0; p2<6; ++p2) *(short8*)(op + p2*8) = *(short8*)&v[p2*8];
    }
  } else {
    int r = (b-1569)*256 + t;
    if (r < NE){
      const float4* ap = (const float4*)(ef + (size_t)r*16);
      unsigned short* op = efb + (size_t)r*16;
      *(short8*)op       = cvt8pk(ap[0], ap[1]);
      *(short8*)(op + 8) = cvt8pk(ap[2], ap[3]);
    }
  }
}

// ========== kscatter: two-level scatter ==========
__global__ __launch_bounds__(1024) void kscatter(const int* __restrict__ eidx,
    const int* __restrict__ bidx, int* __restrict__ eg,
    int* __restrict__ cnt, int* __restrict__ perm2d){
  __shared__ int h[NG];
  __shared__ int base[NG];
  const int b = blockIdx.x, t = threadIdx.x;
  h[t] = 0;
  __syncthreads();
  const int per = NE / 64;            // 9375, exact
  const int lo = b*per, hi = lo + per;
  for (int e = lo + t; e < hi; e += 1024){
    int g = bidx[eidx[e]];
    eg[e] = g;
    atomicAdd(&h[g], 1);
  }
  __syncthreads();
  int c = h[t];
  if (c > 0) base[t] = atomicAdd(&cnt[t], c);
  h[t] = 0;
  __syncthreads();
  for (int e = lo + t; e < hi; e += 1024){
    int g = eg[e];
    int p = base[g] + atomicAdd(&h[g], 1);
    if (p < ECAP) perm2d[(g << 10) + p] = e;
  }
}

// ========== kedge: 32x32x16 MFMA, LDS-staged edge features, 8 waves/block ==========
// block covers graph g = bid>>1, cols (bid&1)*256 + wid*32
__global__ __launch_bounds__(512) void kedge(
    const unsigned short* __restrict__ efb, const int* __restrict__ perm2d,
    const int* __restrict__ cnt, const unsigned short* __restrict__ w1eT16,
    const float* __restrict__ b1e_s, const float* __restrict__ pcoef,
    float* __restrict__ S){
  __shared__ short lds[2][32*40];      // stride 40 shorts (80B) per edge row
  const int t = threadIdx.x;
  const int lane = t & 63, wid = t >> 6;
  const int hi = lane >> 5;
  const int g = blockIdx.x >> 1;
  const int col = ((blockIdx.x & 1) << 8) + (wid << 5) + (lane & 31);
  const float C0 = pcoef[0], C1 = pcoef[1], C2 = pcoef[2], C3 = pcoef[3];
  const float C4 = pcoef[4], C5 = pcoef[5], C6 = pcoef[6], C7 = pcoef[7];
  short8 bfr = *(const short8*)(w1eT16 + col*16 + (hi<<3));
  float bv = b1e_s[col];
  f32x16 bias16;
#pragma unroll
  for (int i=0;i<16;++i) bias16[i] = bv;
  f32x2 aX = {0.f,0.f}, aP = {0.f,0.f};
  const int s1 = cnt[g];
  if (s1 > 0){
    const int base = g << 10;
    const int nch = (s1 + 31) >> 5;
    short8 a1;
    if (t < 64){
      int r0 = min(t & 31, s1-1);
      int r1 = min(32 + (t & 31), s1-1);
      int e0 = perm2d[base + r0];
      int e1 = perm2d[base + r1];
      short8 a0 = *(const short8*)(efb + (size_t)e0*16 + ((t>>5)<<3));
      *(short8*)&lds[0][(t&31)*40 + ((t>>5)<<3)] = a0;
      a1 = *(const short8*)(efb + (size_t)e1*16 + ((t>>5)<<3));
    }
    __syncthreads();
    for (int ch=0; ch<nch; ++ch){
      short8 af = *(const short8*)&lds[ch&1][(lane&31)*40 + (hi<<3)];
      if (t < 64){
        if (ch+1 < nch) *(short8*)&lds[(ch+1)&1][(t&31)*40 + ((t>>5)<<3)] = a1;
        int r2 = min((ch+2)*32 + (t & 31), s1-1);
        int e2 = perm2d[base + r2];
        a1 = *(const short8*)(efb + (size_t)e2*16 + ((t>>5)<<3));
      }
      __syncthreads();
      f32x16 acc = __builtin_amdgcn_mfma_f32_32x32x16_bf16(af, bfr, bias16, 0, 0, 0);
      const int vr = s1 - ch*32;
      if (vr >= 32){
#pragma unroll
        for (int i=0;i<8;++i){
          f32x2 xp = {acc[2*i], acc[2*i+1]};
          g2(xp, aX, aP, C0,C1,C2,C3,C4,C5,C6,C7);
        }
      } else {
#pragma unroll
        for (int i=0;i<8;++i){
          int r0 = ((2*i)&3) + (((2*i)>>2)<<3) + (hi<<2);
          f32x2 xp = { (r0 < vr) ? acc[2*i] : 0.f,
                       (r0+1 < vr) ? acc[2*i+1] : 0.f };
          g2(xp, aX, aP, C0,C1,C2,C3,C4,C5,C6,C7);
        }
      }
    }
  }
  float ssum = __builtin_fmaf(SQ2, aX[0]+aX[1], aP[0]+aP[1]);
  ssum += __shfl_xor(ssum, 32);
  if (lane < 32) S[(size_t)g*1024 + 512 + col] = ssum;
}

// ========== knode: 32x32x16 MFMA x3 (K=48), contiguous rows, 4 waves/block ==========
// block covers graph g = bid>>2, cols (bid&3)*128 + wid*32
__global__ __launch_bounds__(256) void knode(
    const unsigned short* __restrict__ nf48, const int* __restrict__ nstart,
    const unsigned short* __restrict__ w1n48T, const float* __restrict__ b1n_s,
    const float* __restrict__ pcoef, float* __restrict__ S){
  const int t = threadIdx.x;
  const int lane = t & 63, wid = t >> 6;
  const int hi = lane >> 5;
  const int g = blockIdx.x >> 2;
  const int col = ((blockIdx.x & 3) << 7) + (wid << 5) + (lane & 31);
  const float C0 = pcoef[0], C1 = pcoef[1], C2 = pcoef[2], C3 = pcoef[3];
  const float C4 = pcoef[4], C5 = pcoef[5], C6 = pcoef[6], C7 = pcoef[7];
  const unsigned short* bp = w1n48T + col*48 + (hi<<3);
  short8 bf0 = *(const short8*)(bp);
  short8 bf1 = *(const short8*)(bp + 16);
  short8 bf2 = *(const short8*)(bp + 32);
  float bv = b1n_s[col];
  f32x16 bias16;
#pragma unroll
  for (int i=0;i<16;++i) bias16[i] = bv;
  f32x2 aX = {0.f,0.f}, aP = {0.f,0.f};
  const int s0 = nstart[g], s1 = nstart[g+1];
  const int nch = (s1 - s0 + 31) >> 5;
  for (int ch=0; ch<nch; ++ch){
    int rb = s0 + ch*32;
    int ar = min(rb + (lane & 31), s1-1);
    const unsigned short* apn = nf48 + (size_t)ar*48 + (hi<<3);
    short8 a0 = *(const short8*)(apn);
    short8 a1 = *(const short8*)(apn + 16);
    short8 a2 = *(const short8*)(apn + 32);
    f32x16 acc = __builtin_amdgcn_mfma_f32_32x32x16_bf16(a0, bf0, bias16, 0, 0, 0);
    acc = __builtin_amdgcn_mfma_f32_32x32x16_bf16(a1, bf1, acc, 0, 0, 0);
    acc = __builtin_amdgcn_mfma_f32_32x32x16_bf16(a2, bf2, acc, 0, 0, 0);
    const int vr = s1 - rb;
    if (vr >= 32){
#pragma unroll
      for (int i=0;i<8;++i){
        f32x2 xp = {acc[2*i], acc[2*i+1]};
        g2(xp, aX, aP, C0,C1,C2,C3,C4,C5,C6,C7);
      }
    } else {
#pragma unroll
      for (int i=0;i<8;++i){
        int r0 = ((2*i)&3) + (((2*i)>>2)<<3) + (hi<<2);
        f32x2 xp = { (r0 < vr) ? acc[2*i] : 0.f,
                     (r0+1 < vr) ? acc[2*i+1] : 0.f };
        g2(xp, aX, aP, C0,C1,C2,C3,C4,C5,C6,C7);
      }
    }
  }
  float ssum = __builtin_fmaf(SQ2, aX[0]+aX[1], aP[0]+aP[1]);
  ssum += __shfl_xor(ssum, 32);
  if (lane < 32) S[(size_t)g*1024 + col] = ssum;
}

// ========== LDS-free bf16 split (hi+lo) MFMA GEMM, 16-col tiles (2 WG/CU) ==========
// G1 mode (gf!=null): out = acc + gf + cn*b2n + ce*b2e ; else gelu(bn(acc+bias))
__global__ __launch_bounds__(256) void kgemm3(const float* __restrict__ A, int lda, int nkc,
    const float* __restrict__ B0, const float* __restrict__ B1,
    float* __restrict__ out,
    const float* __restrict__ gf, const int* __restrict__ nstart, const int* __restrict__ cnt,
    const float* __restrict__ b2n, const float* __restrict__ b2e,
    const float* __restrict__ bias, const float* __restrict__ gam, const float* __restrict__ bet){
  const int t = threadIdx.x, lane = t & 63, w = t >> 6;
  const int q = lane >> 4, m = lane & 15;
  const int c0 = blockIdx.x*16, r0 = blockIdx.y*64 + w*16;
  f32x4 acc = {0.f,0.f,0.f,0.f};
  const float* ap = A + (size_t)(r0 + m)*lda + (q<<3);
  for (int kc = 0; kc < nkc; ++kc){
    const int ko = kc*32;
    float4 x = *(const float4*)(ap + ko);
    float4 y = *(const float4*)(ap + ko + 4);
    float v[8] = {x.x,x.y,x.z,x.w,y.x,y.y,y.z,y.w};
    short8 ah, al;
    split8(v, &ah, &al);
    const float* Bp = (kc < 16) ? B0 : B1;
    const float* bp = Bp + (size_t)((kc & 15)*32 + (q<<3))*HH + c0 + m;
    float bvv[8];
#pragma unroll
    for (int j=0;j<8;++j) bvv[j] = bp[(size_t)j*HH];
    short8 bh, bl;
    split8(bvv, &bh, &bl);
    acc = __builtin_amdgcn_mfma_f32_16x16x32_bf16(ah, bh, acc, 0, 0, 0);
    acc = __builtin_amdgcn_mfma_f32_16x16x32_bf16(ah, bl, acc, 0, 0, 0);
    acc = __builtin_amdgcn_mfma_f32_16x16x32_bf16(al, bh, acc, 0, 0, 0);
  }
  const float rs = 0.99999500003750f;
  const int c = c0 + m;
  if (gf){
    const float bnv = b2n[c], bev = b2e[c];
#pragma unroll
    for (int i=0;i<4;++i){
      int r = r0 + q*4 + i;
      float cn = (float)(nstart[r+1] - nstart[r]);
      float ce = (float)cnt[r];
      out[(size_t)r*HH + c] = acc[i] + gf[(size_t)r*HH + c] + cn*bnv + ce*bev;
    }
  } else {
    const float sc = gam[c]*rs, bi = bias[c], be = bet[c];
#pragma unroll
    for (int i=0;i<4;++i){
      int r = r0 + q*4 + i;
      out[(size_t)r*HH + c] = gelu_f((acc[i] + bi)*sc + be);
    }
  }
}

// ========== final 512 -> 2 linear ==========
__global__ __launch_bounds__(256) void kfinal(const float* __restrict__ x2, const float* __restrict__ w3,
    const float* __restrict__ b3, float* __restrict__ out){
  const int lane = threadIdx.x & 63, wv = threadIdx.x >> 6;
  const int r = blockIdx.x*4 + wv;
  float a0 = 0.f, a1 = 0.f;
#pragma unroll
  for (int tt=0; tt<8; ++tt){
    int k = lane + tt*64;
    float x = x2[(size_t)r*HH + k];
    a0 = __builtin_fmaf(x, w3[2*k], a0);
    a1 = __builtin_fmaf(x, w3[2*k+1], a1);
  }
#pragma unroll
  for (int d=1; d<64; d<<=1){ a0 += __shfl_xor(a0, d); a1 += __shfl_xor(a1, d); }
  if (lane == 0){ out[r*2] = a0 + b3[0]; out[r*2+1] = a1 + b3[1]; }
}

extern "C" void kernel_launch(void* const* d_in, const int* in_sizes, int n_in,
                              void* d_out, int out_size, void* d_ws, size_t ws_size,
                              hipStream_t stream) {
  const float* nf    = (const float*)d_in[0];
  const float* ef    = (const float*)d_in[1];
  const float* gf    = (const float*)d_in[2];
  const float* dp    = (const float*)d_in[3];
  const int*   ny    = (const int*)d_in[4];
  const int*   bidx  = (const int*)d_in[5];
  const int*   eidx  = (const int*)d_in[6];
  const float* nfw1  = (const float*)d_in[7];
  const float* nfb1  = (const float*)d_in[8];
  const float* nfg1  = (const float*)d_in[9];
  const float* nfbe1 = (const float*)d_in[10];
  const float* w2n   = (const float*)d_in[11];
  const float* b2n   = (const float*)d_in[12];
  const float* efw1  = (const float*)d_in[13];
  const float* efb1  = (const float*)d_in[14];
  const float* efg1  = (const float*)d_in[15];
  const float* efbe1 = (const float*)d_in[16];
  const float* w2e   = (const float*)d_in[17];
  const float* b2e   = (const float*)d_in[18];
  const float* ow1   = (const float*)d_in[19];
  const float* ob1   = (const float*)d_in[20];
  const float* og1   = (const float*)d_in[21];
  const float* obe1  = (const float*)d_in[22];
  const float* ow2   = (const float*)d_in[23];
  const float* ob2   = (const float*)d_in[24];
  const float* og2   = (const float*)d_in[25];
  const float* obe2  = (const float*)d_in[26];
  const float* ow3   = (const float*)d_in[27];
  const float* ob3   = (const float*)d_in[28];

  unsigned char* p = (unsigned char*)d_ws;
  float* S      = (float*)p;                 p += (size_t)NG*1024*4;  // 4MB
  int*   perm2d = (int*)p;                   p += (size_t)NG*ECAP*4;  // 4MB
  unsigned short* nf48 = (unsigned short*)p; p += (size_t)NN*48*2;    // 19.2MB (reused)
  unsigned short* efb  = (unsigned short*)p; p += (size_t)NE*16*2;    // 19.2MB
  unsigned short* w1n48T = (unsigned short*)p; p += 512*48*2;
  unsigned short* w1eT16 = (unsigned short*)p; p += 512*16*2;
  float* b1n_s  = (float*)p;                 p += 512*4;
  float* b1e_s  = (float*)p;                 p += 512*4;
  int* nstart   = (int*)p;                   p += 1032*4;
  int* cnt      = (int*)p;                   p += NG*4;
  float* pcoef  = (float*)p;                 p += 64;
  // eg aliases S (dead before kedge/knode write S)
  int* eg = (int*)S;
  // gh/xg2/x2f alias nf48 region (dead after knode)
  float* gh  = (float*)nf48;
  float* xg2 = gh  + (size_t)NG*HH;
  float* x2f = xg2 + (size_t)NG*HH;

  kpre<<<3913, 256, 0, stream>>>(nfw1, nfb1, nfg1, nfbe1, efw1, efb1, efg1, efbe1,
                                 w1n48T, w1eT16, b1n_s, b1e_s, bidx, nstart, cnt,
                                 pcoef, nf, dp, ny, ef, nf48, efb);
  kscatter<<<64, 1024, 0, stream>>>(eidx, bidx, eg, cnt, perm2d);
  kedge<<<2048, 512, 0, stream>>>(efb, perm2d, cnt, w1eT16, b1e_s, pcoef, S);
  knode<<<4096, 256, 0, stream>>>(nf48, nstart, w1n48T, b1n_s, pcoef, S);
  // G1: gh = S @ [w2n;w2e] + gf + cn*b2n + ce*b2e
  kgemm3<<<dim3(32,16), 256, 0, stream>>>(S, 1024, 32, w2n, w2e, gh,
                                          gf, nstart, cnt, b2n, b2e,
                                          nullptr, nullptr, nullptr);
  // G2: xg2 = gelu(bn(gh @ ow1 + ob1))
  kgemm3<<<dim3(32,16), 256, 0, stream>>>(gh, 512, 16, ow1, ow1, xg2,
                                          nullptr, nullptr, nullptr, nullptr, nullptr,
                                          ob1, og1, obe1);
  // G3: x2f = gelu(bn(xg2 @ ow2 + ob2))
  kgemm3<<<dim3(32,16), 256, 0, stream>>>(xg2, 512, 16, ow2, ow2, x2f,
                                          nullptr, nullptr, nullptr, nullptr, nullptr,
                                          ob2, og2, obe2);
  kfinal<<<NG/4, 256, 0, stream>>>(x2f, ow3, ob3, (float*)d_out);
}